// Round 8
// baseline (82.635 us; speedup 1.0000x reference)
//
#include <hip/hip_runtime.h>
#include <math.h>

namespace {
constexpr int N_ = 2048;
constexpr int D_ = 128;
constexpr int K_ = 8;
constexpr int M_ = 64;
constexpr float JIT = 1e-5f;
constexpr float L2E = 1.4426950408889634f;
constexpr float LN2 = 0.6931471805599453f;

constexpr int NWORK = 256;   // worker blocks (psi2 tasks); block NWORK = LA block
constexpr int NPREP = 8;
constexpr int NRED  = 16;

// ws float offsets (OFF_BAR holds 16 ints, zeroed by hipMemsetAsync each launch)
constexpr int OFF_BAR  = 0;
constexpr int OFF_ARR2 = 16;                    // N*16 : per-n [a[8], ib2s[8]]
constexpr int OFF_C2   = OFF_ARR2 + N_ * 16;    // N
constexpr int OFF_P1Y  = OFF_C2 + N_;           // 8*64
constexpr int OFF_P2P  = OFF_P1Y + 512;         // 16*4096 psi2 partials
constexpr int OFF_PSI2 = OFF_P2P + 16 * 4096;   // 4096 reduced psi2 (left folded)
}

struct F8 { float f[8]; };

__device__ __forceinline__ float f4e(float4 v, int e) {
  return (e == 0) ? v.x : (e == 1) ? v.y : (e == 2) ? v.z : v.w;
}

// ---- grid barrier: arrive/wait on monotonically-increasing counters --------
__device__ __forceinline__ void bar_arrive(int* c) {
  __syncthreads();                       // all block stores done
  if (threadIdx.x == 0) { __threadfence(); atomicAdd(c, 1); }
}
__device__ __forceinline__ void bar_wait(int* c, int target) {
  if (threadIdx.x == 0) {
    while (__hip_atomic_load(c, __ATOMIC_RELAXED, __HIP_MEMORY_SCOPE_AGENT) < target)
      __builtin_amdgcn_s_sleep(2);
    __threadfence();                     // acquire: invalidate stale lines
  }
  __syncthreads();
}

// unrolled 2x2-block symmetric sweep: reg (column `lane` of SPD A) ->
// column of (-A^{-1}); returns log2(det A). rowbuf is [parity*2 + A/B][64].
__device__ __forceinline__ float sweep2x2(float* reg, float (*rowbuf)[M_], int lane) {
  float ld = 0.f;
#pragma unroll
  for (int p = 0; p < M_; p += 2) {
    const int par = (p >> 1) & 1;
    float* rbA = rowbuf[par * 2 + 0];
    float* rbB = rowbuf[par * 2 + 1];
    rbA[lane] = reg[p];
    rbB[lane] = reg[p + 1];
    float4 ra[16], rb[16];
    const float4* rbAq = reinterpret_cast<const float4*>(rbA);
    const float4* rbBq = reinterpret_cast<const float4*>(rbB);
#pragma unroll
    for (int q = 0; q < 16; q++) { ra[q] = rbAq[q]; rb[q] = rbBq[q]; }

    const float P00 = f4e(ra[p >> 2], p & 3);
    const float P01 = f4e(ra[(p + 1) >> 2], (p + 1) & 3);
    const float P11 = f4e(rb[(p + 1) >> 2], (p + 1) & 3);
    const float det = fmaf(P00, P11, -P01 * P01);
    const float idet = __builtin_amdgcn_rcpf(det);
    ld += __log2f(det);
    const float Pi00 =  P11 * idet;
    const float Pi01 = -P01 * idet;
    const float Pi11 =  P00 * idet;

    const bool isp = (lane == p), isq = (lane == p + 1);
    const float a0 = reg[p], a1 = reg[p + 1];
    const float w0 = isp ? Pi00 : (isq ? Pi01 : fmaf(Pi00, a0, Pi01 * a1));
    const float w1 = isp ? Pi01 : (isq ? Pi11 : fmaf(Pi01, a0, Pi11 * a1));
    const float t0 = isp ? (1.f - w0) : (isq ? -w0 : w0);
    const float t1 = isq ? (1.f - w1) : (isp ? -w1 : w1);
    const float f0 = (isp || isq) ? -w0 : w0;
    const float f1 = (isp || isq) ? -w1 : w1;
#pragma unroll
    for (int q = 0; q < 16; q++) {
      const float4 va = ra[q], vb = rb[q];
      reg[4 * q + 0] = fmaf(-t1, vb.x, fmaf(-t0, va.x, reg[4 * q + 0]));
      reg[4 * q + 1] = fmaf(-t1, vb.y, fmaf(-t0, va.y, reg[4 * q + 1]));
      reg[4 * q + 2] = fmaf(-t1, vb.z, fmaf(-t0, va.z, reg[4 * q + 2]));
      reg[4 * q + 3] = fmaf(-t1, vb.w, fmaf(-t0, va.w, reg[4 * q + 3]));
    }
    reg[p] = f0;
    reg[p + 1] = f1;
  }
  return ld;
}

// ---------------------------------------------------------------------------
// Fused kernel, grid = 257 blocks x 256 threads (all co-resident).
//  blocks 0..7   : prep chunk b (+ fused Psi1^T Y partial), then worker path
//  blocks 0..255 : psi2 task b after bar0; blocks 0..15 reduce after bar1
//  block 256     : Kuu sweep + YY + KL (overlapped), then after bar2 the
//                  KuPsi2 sweep + trace + combine -> out[0]
// ---------------------------------------------------------------------------
__global__ __launch_bounds__(256) void vdmgp_fused(
    const float* __restrict__ X, const float* __restrict__ Y,
    const float* __restrict__ qmu, const float* __restrict__ qcov,
    const float* __restrict__ Z,
    const float* __restrict__ sfp, const float* __restrict__ nvp,
    float* __restrict__ ws, float* __restrict__ out) {
  // worker LDS
  __shared__ float smu[D_ * K_];
  __shared__ float scov[D_ * K_];
  __shared__ float sa1[256 * 16];
  __shared__ float scy[256];
  __shared__ float red[256];
  __shared__ float sa[128 * 16];
  __shared__ float sc[128];
  // LA-block LDS
  __shared__ float zl[M_][9];
  __shared__ float kuiL[M_][M_];
  __shared__ float P2s[M_][M_];
  __shared__ __align__(16) float rowbuf[4][M_];
  __shared__ float pysL[M_];
  __shared__ float scalL[8];

  int* bar = (int*)ws;
  const int tid = threadIdx.x;
  const int b = blockIdx.x;
  const float sf = sfp[0];

  if (b == NWORK) {
    // ---------------- LA block ----------------
    for (int idx = tid; idx < M_ * K_; idx += 256) zl[idx >> 3][idx & 7] = Z[idx];
    __syncthreads();
    const int lane = tid & 63;
    const int wave = tid >> 6;
    if (wave == 0) {
      float zj[K_];
#pragma unroll
      for (int k = 0; k < K_; k++) zj[k] = zl[lane][k];
      float reg[M_];
#pragma unroll
      for (int i = 0; i < M_; i++) {
        float sq = 0.f;
#pragma unroll
        for (int k = 0; k < K_; k++) { const float dd = zl[i][k] - zj[k]; sq = fmaf(dd, dd, sq); }
        reg[i] = exp2f(-0.5f * L2E * sq) + ((i == lane) ? JIT : 0.f);
      }
      const float ld1 = sweep2x2(reg, rowbuf, lane);
#pragma unroll
      for (int i = 0; i < M_; i++) kuiL[i][lane] = reg[i];   // -Kuu^{-1}
      if (lane == 0) scalL[2] = LN2 * ld1;
    } else if (wave == 1) {
      float yy = 0.f;
#pragma unroll
      for (int t = 0; t < 32; t++) { const float y = Y[t * 64 + lane]; yy = fmaf(y, y, yy); }
#pragma unroll
      for (int off = 32; off > 0; off >>= 1) yy += __shfl_down(yy, off, 64);
      if (lane == 0) scalL[0] = yy;
    } else if (wave == 2) {
      const int k = lane >> 3;
      const int d0 = (lane & 7) * 16;
      float slog = 0.f, srow = 0.f;
#pragma unroll
      for (int t = 0; t < 16; t++) {
        const float qc = qcov[k * D_ + d0 + t];
        const float qm = qmu[k * D_ + d0 + t];
        slog += logf(qc);
        srow += qc + qm * qm;
      }
#pragma unroll
      for (int off = 4; off > 0; off >>= 1) {
        slog += __shfl_down(slog, off, 8);
        srow += __shfl_down(srow, off, 8);
      }
      float klr = ((lane & 7) == 0)
          ? (slog - (float)D_ * logf(srow) + (float)D_ * logf((float)D_)) : 0.f;
      klr += __shfl_down(klr, 32, 64);
      klr += __shfl_down(klr, 16, 64);
      klr += __shfl_down(klr, 8, 64);
      if (lane == 0) scalL[1] = klr;
    }

    bar_wait(&bar[2], NRED);            // reduced psi2 ready

    // stage psi2 (left folded) coalesced into LDS
#pragma unroll
    for (int t = 0; t < 16; t++) {
      const int idx = t * 256 + tid;
      (&P2s[0][0])[idx] = ws[OFF_PSI2 + idx];
    }
    if (tid < M_) {
      float s = 0.f;
#pragma unroll
      for (int c = 0; c < 8; c++) s += ws[OFF_P1Y + c * M_ + tid];
      pysL[tid] = sf * s;
    }
    __syncthreads();

    const float s2v = nvp[0];
    if (wave == 0) {
      float zj[K_];
#pragma unroll
      for (int k = 0; k < K_; k++) zj[k] = zl[lane][k];
      float reg[M_];
#pragma unroll
      for (int i = 0; i < M_; i++) {
        float sq = 0.f;
#pragma unroll
        for (int k = 0; k < K_; k++) { const float dd = zl[i][k] - zj[k]; sq = fmaf(dd, dd, sq); }
        const float jit = (i == lane) ? JIT : 0.f;
        const float kj = exp2f(-0.5f * L2E * sq) + jit;
        reg[i] = fmaf(s2v, kj, P2s[i][lane] + jit);
      }
      const float ld2 = sweep2x2(reg, rowbuf, lane);
      float local = 0.f;
#pragma unroll
      for (int i = 0; i < M_; i++) local = fmaf(reg[i], pysL[i], local);
      local *= pysL[lane];
#pragma unroll
      for (int off = 32; off > 0; off >>= 1) local += __shfl_down(local, off, 64);
      if (lane == 0) { scalL[6] = LN2 * ld2; scalL[7] = -local; }
    } else if (wave == 1) {
      float acc = 0.f;
#pragma unroll
      for (int i = 0; i < M_; i++) acc = fmaf(kuiL[i][lane], P2s[i][lane], acc);
#pragma unroll
      for (int off = 32; off > 0; off >>= 1) acc += __shfl_down(acc, off, 64);
      if (lane == 0) scalL[5] = -acc;   // trace
    }
    __syncthreads();

    if (tid == 0) {
      const float YY = scalL[0], KL = scalL[1], ld1 = scalL[2];
      const float tr = scalL[5], ld2 = scalL[6], quad = scalL[7];
      const float inv = 1.0f / s2v;
      const float F1 = -(float)N_ * 1.8378770664093453f
                     - (float)(N_ - M_) * logf(s2v)
                     + (ld1 - ld2)
                     - YY * inv
                     + quad * inv
                     - (float)N_ * sf * sf * inv
                     + tr * inv;
      out[0] = 0.5f * (F1 + KL);
    }
    return;
  }

  // ---------------- worker blocks 0..255 ----------------
  if (b < NPREP) {
    // prep chunk b: n in [256b, 256b+256) + fused Psi1^T Y partial
    for (int idx = tid; idx < K_ * D_; idx += 256) {
      int k = idx >> 7, d = idx & 127;
      smu[d * K_ + k]  = qmu[idx];
      scov[d * K_ + k] = qcov[idx];
    }
    __syncthreads();

    const int n = b * 256 + tid;
    float a[K_], s2[K_];
#pragma unroll
    for (int k = 0; k < K_; k++) { a[k] = 0.f; s2[k] = 0.f; }
    const float4* xrow = reinterpret_cast<const float4*>(X + n * D_);
    for (int dq = 0; dq < D_ / 4; dq++) {
      float4 xv = xrow[dq];
      float xs[4] = {xv.x, xv.y, xv.z, xv.w};
#pragma unroll
      for (int t = 0; t < 4; t++) {
        const int d = dq * 4 + t;
        const float x = xs[t];
        const float xx = x * x;
        F8 mu = *reinterpret_cast<const F8*>(&smu[d * K_]);
        F8 cv = *reinterpret_cast<const F8*>(&scov[d * K_]);
#pragma unroll
        for (int k = 0; k < K_; k++) {
          a[k]  = fmaf(mu.f[k], x, a[k]);
          s2[k] = fmaf(cv.f[k], xx, s2[k]);
        }
      }
    }

    float4 w2[4];
    float prod2 = 1.f, prod1 = 1.f;
#pragma unroll
    for (int k = 0; k < K_; k++) {
      const float b2 = 2.f * s2[k] + 1.f;
      const float b1 = 1.f + s2[k];
      reinterpret_cast<float*>(w2)[k]     = a[k];
      reinterpret_cast<float*>(w2)[8 + k] = L2E / b2;
      sa1[tid * 16 + k]     = a[k];
      sa1[tid * 16 + 8 + k] = 0.5f * L2E / b1;
      prod2 *= rsqrtf(b2);
      prod1 *= rsqrtf(b1);
    }
    float4* a2q = reinterpret_cast<float4*>(ws + OFF_ARR2 + n * 16);
#pragma unroll
    for (int e = 0; e < 4; e++) a2q[e] = w2[e];
    (ws + OFF_C2)[n] = prod2;
    scy[tid] = prod1 * Y[n];
    __syncthreads();

    // Psi1^T Y over this block's 256 n's (LDS resident)
    const int m = tid & 63;
    const int stripe = tid >> 6;
    float zm[K_];
#pragma unroll
    for (int k = 0; k < K_; k++) zm[k] = Z[m * K_ + k];
    float acc = 0.f;
    for (int t = 0; t < 64; t++) {
      const int nl = stripe * 64 + t;
      const F8 av = *reinterpret_cast<const F8*>(&sa1[nl * 16]);
      const F8 ib = *reinterpret_cast<const F8*>(&sa1[nl * 16 + 8]);
      float s = 0.f;
#pragma unroll
      for (int k = 0; k < K_; k++) {
        const float d = av.f[k] - zm[k];
        s = fmaf(d * d, ib.f[k], s);
      }
      acc = fmaf(scy[nl], exp2f(-s), acc);
    }
    red[tid] = acc;
    __syncthreads();
    if (tid < 64)
      (ws + OFF_P1Y)[b * 64 + tid] =
          red[tid] + red[64 + tid] + red[128 + tid] + red[192 + tid];

    bar_arrive(&bar[0]);
  }

  bar_wait(&bar[0], NPREP);             // prep data ready

  // psi2 task b: chunk (b>>4) of 128 n, pair-block (b&15) of 256 pairs
  {
    const int chunk = b >> 4;
    const int nbase = chunk * 128;
    const float4* src = reinterpret_cast<const float4*>(ws + OFF_ARR2 + nbase * 16);
    float4* dst = reinterpret_cast<float4*>(sa);
    for (int idx = tid; idx < 128 * 4; idx += 256) dst[idx] = src[idx];
    if (tid < 128) sc[tid] = (ws + OFF_C2)[nbase + tid];
    __syncthreads();

    const int pair = (b & 15) * 256 + tid;
    const int i = pair >> 6, j = pair & 63;
    float zb[K_];
#pragma unroll
    for (int k = 0; k < K_; k++) zb[k] = 0.5f * (Z[i * K_ + k] + Z[j * K_ + k]);

    float acc = 0.f;
    for (int nl = 0; nl < 128; nl++) {
      const F8 av = *reinterpret_cast<const F8*>(&sa[nl * 16]);
      const F8 ib = *reinterpret_cast<const F8*>(&sa[nl * 16 + 8]);
      float s = 0.f;
#pragma unroll
      for (int k = 0; k < K_; k++) {
        const float t = av.f[k] - zb[k];
        s = fmaf(t * t, ib.f[k], s);
      }
      acc = fmaf(sc[nl], exp2f(-s), acc);
    }
    (ws + OFF_P2P)[chunk * 4096 + pair] = acc;
  }

  bar_arrive(&bar[1]);

  if (b < NRED) {
    bar_wait(&bar[1], NWORK);           // all psi2 partials ready
    // reduce pairs [256b, 256b+256) over 16 chunks, fold `left`
    const int p = b * 256 + tid;
    float acc = 0.f;
#pragma unroll
    for (int c = 0; c < 16; c++) acc += ws[OFF_P2P + c * 4096 + p];
    const int i = p >> 6, j = p & 63;
    float sq = 0.f;
#pragma unroll
    for (int k = 0; k < K_; k++) {
      const float dd = Z[i * K_ + k] - Z[j * K_ + k];
      sq = fmaf(dd, dd, sq);
    }
    ws[OFF_PSI2 + p] = sf * sf * exp2f(-0.25f * L2E * sq) * acc;

    bar_arrive(&bar[2]);
  }
}

extern "C" void kernel_launch(void* const* d_in, const int* in_sizes, int n_in,
                              void* d_out, int out_size, void* d_ws, size_t ws_size,
                              hipStream_t stream) {
  const float* X    = (const float*)d_in[0];
  const float* Y    = (const float*)d_in[1];
  const float* qmu  = (const float*)d_in[2];
  const float* qcov = (const float*)d_in[3];
  const float* Z    = (const float*)d_in[4];
  const float* sfp  = (const float*)d_in[5];
  const float* nvp  = (const float*)d_in[6];
  float* ws  = (float*)d_ws;
  float* out = (float*)d_out;

  hipMemsetAsync(d_ws, 0, 64, stream);   // zero barrier counters (capturable)
  vdmgp_fused<<<NWORK + 1, 256, 0, stream>>>(X, Y, qmu, qcov, Z, sfp, nvp, ws, out);
}

// Round 9
// 73.800 us; speedup vs baseline: 1.1197x; 1.1197x over previous
//
#include <hip/hip_runtime.h>
#include <math.h>

namespace {
constexpr int N_ = 2048;
constexpr int D_ = 128;
constexpr int K_ = 8;
constexpr int M_ = 64;
constexpr float JIT = 1e-5f;
constexpr float L2E = 1.4426950408889634f;
constexpr float LN2 = 0.6931471805599453f;

// ws float offsets (OFF_BAR: 16 ints, zeroed via hipMemsetAsync each launch)
constexpr int OFF_BAR  = 0;
constexpr int OFF_ARR2 = 16;                    // N*16 : per-n [a[8], ib2s[8]]
constexpr int OFF_C2   = OFF_ARR2 + N_ * 16;    // N
constexpr int OFF_ARR1 = OFF_C2 + N_;           // N*16 : per-n [a[8], ib1s[8]]
constexpr int OFF_CY   = OFF_ARR1 + N_ * 16;    // N
constexpr int OFF_P2P  = OFF_CY + N_;           // 16*4096 psi2 partials
constexpr int OFF_P1Y  = OFF_P2P + 16 * 4096;   // 8*64
constexpr int OFF_KUI  = OFF_P1Y + 512;         // 4096 : -Kuu^{-1}
constexpr int OFF_SC   = OFF_KUI + 4096;        // 3 : YY, KL, log2det(Kuu)
}

struct F8 { float f[8]; };

__device__ __forceinline__ float f4e(float4 v, int e) {
  return (e == 0) ? v.x : (e == 1) ? v.y : (e == 2) ? v.z : v.w;
}

// ---- barrier primitives (single-spinner design) ---------------------------
__device__ __forceinline__ void bar_arrive(int* c) {
  __syncthreads();
  if (threadIdx.x == 0) { __threadfence(); atomicAdd(c, 1); }
}
__device__ __forceinline__ void bar_wait(int* c, int target) {
  if (threadIdx.x == 0) {
    while (__hip_atomic_load(c, __ATOMIC_RELAXED, __HIP_MEMORY_SCOPE_AGENT) < target)
      __builtin_amdgcn_s_sleep(16);
    __threadfence();
  }
  __syncthreads();
}

// unrolled 2x2-block symmetric sweep: reg (column `lane` of SPD A) ->
// column of (-A^{-1}); returns log2(det A). rowbuf is [parity*2 + A/B][64].
__device__ __forceinline__ float sweep2x2(float* reg, float (*rowbuf)[M_], int lane) {
  float ld = 0.f;
#pragma unroll
  for (int p = 0; p < M_; p += 2) {
    const int par = (p >> 1) & 1;
    float* rbA = rowbuf[par * 2 + 0];
    float* rbB = rowbuf[par * 2 + 1];
    rbA[lane] = reg[p];
    rbB[lane] = reg[p + 1];
    float4 ra[16], rb[16];
    const float4* rbAq = reinterpret_cast<const float4*>(rbA);
    const float4* rbBq = reinterpret_cast<const float4*>(rbB);
#pragma unroll
    for (int q = 0; q < 16; q++) { ra[q] = rbAq[q]; rb[q] = rbBq[q]; }

    const float P00 = f4e(ra[p >> 2], p & 3);
    const float P01 = f4e(ra[(p + 1) >> 2], (p + 1) & 3);
    const float P11 = f4e(rb[(p + 1) >> 2], (p + 1) & 3);
    const float det = fmaf(P00, P11, -P01 * P01);
    const float idet = __builtin_amdgcn_rcpf(det);
    ld += __log2f(det);
    const float Pi00 =  P11 * idet;
    const float Pi01 = -P01 * idet;
    const float Pi11 =  P00 * idet;

    const bool isp = (lane == p), isq = (lane == p + 1);
    const float a0 = reg[p], a1 = reg[p + 1];
    const float w0 = isp ? Pi00 : (isq ? Pi01 : fmaf(Pi00, a0, Pi01 * a1));
    const float w1 = isp ? Pi01 : (isq ? Pi11 : fmaf(Pi01, a0, Pi11 * a1));
    const float t0 = isp ? (1.f - w0) : (isq ? -w0 : w0);
    const float t1 = isq ? (1.f - w1) : (isp ? -w1 : w1);
    const float f0 = (isp || isq) ? -w0 : w0;
    const float f1 = (isp || isq) ? -w1 : w1;
#pragma unroll
    for (int q = 0; q < 16; q++) {
      const float4 va = ra[q], vb = rb[q];
      reg[4 * q + 0] = fmaf(-t1, vb.x, fmaf(-t0, va.x, reg[4 * q + 0]));
      reg[4 * q + 1] = fmaf(-t1, vb.y, fmaf(-t0, va.y, reg[4 * q + 1]));
      reg[4 * q + 2] = fmaf(-t1, vb.z, fmaf(-t0, va.z, reg[4 * q + 2]));
      reg[4 * q + 3] = fmaf(-t1, vb.w, fmaf(-t0, va.w, reg[4 * q + 3]));
    }
    reg[p] = f0;
    reg[p + 1] = f1;
  }
  return ld;
}

// ---------------------------------------------------------------------------
// K1: 9 blocks. b<8: prep (per-n stats -> ws). b==8: Kuu^{-1} sweep + YY + KL.
// ---------------------------------------------------------------------------
__global__ __launch_bounds__(256) void vdmgp_k1(
    const float* __restrict__ X, const float* __restrict__ Y,
    const float* __restrict__ qmu, const float* __restrict__ qcov,
    const float* __restrict__ Z, float* __restrict__ ws) {
  __shared__ float smu[D_ * K_];   // [d][k]
  __shared__ float scov[D_ * K_];
  __shared__ float zl[M_][9];
  __shared__ __align__(16) float rowbuf[4][M_];

  const int tid = threadIdx.x;
  const int b = blockIdx.x;

  if (b == 8) {
    for (int idx = tid; idx < M_ * K_; idx += 256) zl[idx >> 3][idx & 7] = Z[idx];
    __syncthreads();
    const int lane = tid & 63;
    const int wave = tid >> 6;
    if (wave == 0) {
      float zj[K_];
#pragma unroll
      for (int k = 0; k < K_; k++) zj[k] = zl[lane][k];
      float reg[M_];
#pragma unroll
      for (int i = 0; i < M_; i++) {
        float sq = 0.f;
#pragma unroll
        for (int k = 0; k < K_; k++) { const float dd = zl[i][k] - zj[k]; sq = fmaf(dd, dd, sq); }
        reg[i] = exp2f(-0.5f * L2E * sq) + ((i == lane) ? JIT : 0.f);
      }
      const float ld = sweep2x2(reg, rowbuf, lane);
#pragma unroll
      for (int i = 0; i < M_; i++) ws[OFF_KUI + i * 64 + lane] = reg[i];
      if (lane == 0) ws[OFF_SC + 2] = LN2 * ld;
    } else if (wave == 1) {
      float yy = 0.f;
#pragma unroll
      for (int t = 0; t < 32; t++) {
        const float y = Y[t * 64 + lane];
        yy = fmaf(y, y, yy);
      }
#pragma unroll
      for (int off = 32; off > 0; off >>= 1) yy += __shfl_down(yy, off, 64);
      if (lane == 0) ws[OFF_SC + 0] = yy;
    } else if (wave == 2) {
      const int k = lane >> 3;
      const int d0 = (lane & 7) * 16;
      float slog = 0.f, srow = 0.f;
#pragma unroll
      for (int t = 0; t < 16; t++) {
        const float qc = qcov[k * D_ + d0 + t];
        const float qm = qmu[k * D_ + d0 + t];
        slog += logf(qc);
        srow += qc + qm * qm;
      }
#pragma unroll
      for (int off = 4; off > 0; off >>= 1) {
        slog += __shfl_down(slog, off, 8);
        srow += __shfl_down(srow, off, 8);
      }
      float klr = ((lane & 7) == 0)
          ? (slog - (float)D_ * logf(srow) + (float)D_ * logf((float)D_)) : 0.f;
      klr += __shfl_down(klr, 32, 64);
      klr += __shfl_down(klr, 16, 64);
      klr += __shfl_down(klr, 8, 64);
      if (lane == 0) ws[OFF_SC + 1] = klr;
    }
    return;
  }

  // prep: one n per thread
  for (int idx = tid; idx < K_ * D_; idx += 256) {
    int k = idx >> 7, d = idx & 127;
    smu[d * K_ + k]  = qmu[idx];
    scov[d * K_ + k] = qcov[idx];
  }
  __syncthreads();

  const int n = b * 256 + tid;
  float a[K_], s2[K_];
#pragma unroll
  for (int k = 0; k < K_; k++) { a[k] = 0.f; s2[k] = 0.f; }

  const float4* xrow = reinterpret_cast<const float4*>(X + n * D_);
#pragma unroll 2
  for (int dq = 0; dq < D_ / 4; dq++) {
    float4 xv = xrow[dq];
    float xs[4] = {xv.x, xv.y, xv.z, xv.w};
#pragma unroll
    for (int t = 0; t < 4; t++) {
      const int d = dq * 4 + t;
      const float x = xs[t];
      const float xx = x * x;
      F8 mu = *reinterpret_cast<const F8*>(&smu[d * K_]);
      F8 cv = *reinterpret_cast<const F8*>(&scov[d * K_]);
#pragma unroll
      for (int k = 0; k < K_; k++) {
        a[k]  = fmaf(mu.f[k], x, a[k]);
        s2[k] = fmaf(cv.f[k], xx, s2[k]);
      }
    }
  }

  float4 w2[4], w1[4];
  float prod2 = 1.f, prod1 = 1.f;
#pragma unroll
  for (int k = 0; k < K_; k++) {
    const float b2 = 2.f * s2[k] + 1.f;
    const float b1 = 1.f + s2[k];
    reinterpret_cast<float*>(w2)[k]     = a[k];
    reinterpret_cast<float*>(w2)[8 + k] = L2E / b2;
    reinterpret_cast<float*>(w1)[k]     = a[k];
    reinterpret_cast<float*>(w1)[8 + k] = 0.5f * L2E / b1;
    prod2 *= rsqrtf(b2);
    prod1 *= rsqrtf(b1);
  }
  float4* a2q = reinterpret_cast<float4*>(ws + OFF_ARR2 + n * 16);
  float4* a1q = reinterpret_cast<float4*>(ws + OFF_ARR1 + n * 16);
#pragma unroll
  for (int e = 0; e < 4; e++) { a2q[e] = w2[e]; a1q[e] = w1[e]; }
  (ws + OFF_C2)[n] = prod2;
  (ws + OFF_CY)[n] = prod1 * Y[n];
}

// ---------------------------------------------------------------------------
// K2: 265 blocks.
//   b<256       : psi2 task (chunk b>>4 of 128 n, pairblk b&15) -> bar0
//   256<=b<264  : Psi1^T Y chunk (b-256)                        -> bar1
//   b==264      : sole spinner; reduce + KuPsi2 sweep + trace + combine
// LDS: one 20.5KB pool, carved per path (all 265 blocks co-resident).
// ---------------------------------------------------------------------------
__global__ __launch_bounds__(256, 1) void vdmgp_k2(
    const float* __restrict__ Z,
    const float* __restrict__ sfp, const float* __restrict__ nvp,
    float* __restrict__ ws, float* __restrict__ out) {
  __shared__ __align__(16) float pool[5008];

  int* bar = (int*)ws;
  const int tid = threadIdx.x;
  const int b = blockIdx.x;
  const float sf = sfp[0];

  if (b < 256) {
    // -------- psi2 task --------
    float* sa = pool;           // 128*16
    float* sc = pool + 2048;    // 128
    const int chunk = b >> 4;
    const int nbase = chunk * 128;
    const float4* src = reinterpret_cast<const float4*>(ws + OFF_ARR2 + nbase * 16);
    float4* dst = reinterpret_cast<float4*>(sa);
    for (int idx = tid; idx < 128 * 4; idx += 256) dst[idx] = src[idx];
    if (tid < 128) sc[tid] = (ws + OFF_C2)[nbase + tid];
    __syncthreads();

    const int pair = (b & 15) * 256 + tid;
    const int i = pair >> 6, j = pair & 63;
    float zb[K_];
#pragma unroll
    for (int k = 0; k < K_; k++) zb[k] = 0.5f * (Z[i * K_ + k] + Z[j * K_ + k]);

    float acc = 0.f;
    for (int nl = 0; nl < 128; nl++) {
      const F8 av = *reinterpret_cast<const F8*>(&sa[nl * 16]);
      const F8 ib = *reinterpret_cast<const F8*>(&sa[nl * 16 + 8]);
      float s = 0.f;
#pragma unroll
      for (int k = 0; k < K_; k++) {
        const float t = av.f[k] - zb[k];
        s = fmaf(t * t, ib.f[k], s);
      }
      acc = fmaf(sc[nl], exp2f(-s), acc);
    }
    (ws + OFF_P2P)[chunk * 4096 + pair] = acc;
    bar_arrive(&bar[0]);
    return;
  }

  if (b < 264) {
    // -------- Psi1^T Y chunk --------
    float* sa1 = pool;          // 256*16
    float* scy = pool + 4096;   // 256
    float* red = pool + 4352;   // 256
    const int chunk = b - 256;
    const int nbase = chunk * 256;
    const float4* src = reinterpret_cast<const float4*>(ws + OFF_ARR1 + nbase * 16);
    float4* dst = reinterpret_cast<float4*>(sa1);
#pragma unroll
    for (int r = 0; r < 4; r++) dst[r * 256 + tid] = src[r * 256 + tid];
    scy[tid] = (ws + OFF_CY)[nbase + tid];
    __syncthreads();

    const int m = tid & 63;
    const int stripe = tid >> 6;
    float zm[K_];
#pragma unroll
    for (int k = 0; k < K_; k++) zm[k] = Z[m * K_ + k];

    float acc = 0.f;
    for (int t = 0; t < 64; t++) {
      const int nl = stripe * 64 + t;
      const F8 av = *reinterpret_cast<const F8*>(&sa1[nl * 16]);
      const F8 ib = *reinterpret_cast<const F8*>(&sa1[nl * 16 + 8]);
      float s = 0.f;
#pragma unroll
      for (int k = 0; k < K_; k++) {
        const float d = av.f[k] - zm[k];
        s = fmaf(d * d, ib.f[k], s);
      }
      acc = fmaf(scy[nl], exp2f(-s), acc);
    }
    red[tid] = acc;
    __syncthreads();
    if (tid < 64)
      (ws + OFF_P1Y)[chunk * 64 + tid] =
          red[tid] + red[64 + tid] + red[128 + tid] + red[192 + tid];
    bar_arrive(&bar[1]);
    return;
  }

  // -------- b == 264: LA tail (sole spinner) --------
  float (*P2s)[M_] = reinterpret_cast<float(*)[M_]>(pool);        // 4096
  float (*zl)[9]   = reinterpret_cast<float(*)[9]>(pool + 4096);  // 576
  float (*rowbuf)[M_] = reinterpret_cast<float(*)[M_]>(pool + 4672); // 256
  float* pysL = pool + 4928;                                      // 64
  float* scalL = pool + 4992;                                     // 8

  for (int idx = tid; idx < M_ * K_; idx += 256) zl[idx >> 3][idx & 7] = Z[idx];

  bar_wait(&bar[1], 8);     // p1y partials ready
  bar_wait(&bar[0], 256);   // psi2 partials ready

  if (tid < M_) {
    float s = 0.f;
#pragma unroll
    for (int c = 0; c < 8; c++) s += ws[OFF_P1Y + c * M_ + tid];
    pysL[tid] = sf * s;
  }

  // reduce the 16 psi2 partial chunks, fold `left` (zl staged above; the
  // bar_wait's trailing __syncthreads ordered it before this point)
  const float4* part4 = reinterpret_cast<const float4*>(ws + OFF_P2P);
  const float sf2 = sf * sf;
#pragma unroll
  for (int g = 0; g < 4; g++) {
    const int idx4 = g * 256 + tid;
    float4 acc = {0.f, 0.f, 0.f, 0.f};
#pragma unroll
    for (int c = 0; c < 16; c++) {
      const float4 v = part4[c * 1024 + idx4];
      acc.x += v.x; acc.y += v.y; acc.z += v.z; acc.w += v.w;
    }
    const int i = idx4 >> 4;
    const int j0 = (idx4 & 15) * 4;
    float o[4];
#pragma unroll
    for (int e = 0; e < 4; e++) {
      const int j = j0 + e;
      float sq = 0.f;
#pragma unroll
      for (int k = 0; k < K_; k++) {
        const float dd = zl[i][k] - zl[j][k];
        sq = fmaf(dd, dd, sq);
      }
      o[e] = sf2 * exp2f(-0.25f * L2E * sq) * f4e(acc, e);
    }
    *reinterpret_cast<float4*>(&P2s[i][j0]) = make_float4(o[0], o[1], o[2], o[3]);
  }
  __syncthreads();

  const int lane = tid & 63;
  const int wave = tid >> 6;
  const float s2v = nvp[0];
  if (wave == 0) {
    float zj[K_];
#pragma unroll
    for (int k = 0; k < K_; k++) zj[k] = zl[lane][k];
    float reg[M_];
#pragma unroll
    for (int i = 0; i < M_; i++) {
      float sq = 0.f;
#pragma unroll
      for (int k = 0; k < K_; k++) { const float dd = zl[i][k] - zj[k]; sq = fmaf(dd, dd, sq); }
      const float jit = (i == lane) ? JIT : 0.f;
      const float kj = exp2f(-0.5f * L2E * sq) + jit;
      reg[i] = fmaf(s2v, kj, P2s[i][lane] + jit);
    }
    const float ld2 = sweep2x2(reg, rowbuf, lane);
    float local = 0.f;
#pragma unroll
    for (int i = 0; i < M_; i++) local = fmaf(reg[i], pysL[i], local);
    local *= pysL[lane];
#pragma unroll
    for (int off = 32; off > 0; off >>= 1) local += __shfl_down(local, off, 64);
    if (lane == 0) { scalL[6] = LN2 * ld2; scalL[7] = -local; }
  } else if (wave == 1) {
    const float* kui = ws + OFF_KUI;   // -Kuu^{-1}
    float acc = 0.f;
#pragma unroll
    for (int i = 0; i < M_; i++) acc = fmaf(kui[i * 64 + lane], P2s[i][lane], acc);
#pragma unroll
    for (int off = 32; off > 0; off >>= 1) acc += __shfl_down(acc, off, 64);
    if (lane == 0) scalL[5] = -acc;    // trace
  }
  __syncthreads();

  if (tid == 0) {
    const float YY  = ws[OFF_SC + 0];
    const float KL  = ws[OFF_SC + 1];
    const float ld1 = ws[OFF_SC + 2];
    const float tr = scalL[5], ld2 = scalL[6], quad = scalL[7];
    const float inv = 1.0f / s2v;
    const float F1 = -(float)N_ * 1.8378770664093453f
                   - (float)(N_ - M_) * logf(s2v)
                   + (ld1 - ld2)
                   - YY * inv
                   + quad * inv
                   - (float)N_ * sf * sf * inv
                   + tr * inv;
    out[0] = 0.5f * (F1 + KL);
  }
}

extern "C" void kernel_launch(void* const* d_in, const int* in_sizes, int n_in,
                              void* d_out, int out_size, void* d_ws, size_t ws_size,
                              hipStream_t stream) {
  const float* X    = (const float*)d_in[0];
  const float* Y    = (const float*)d_in[1];
  const float* qmu  = (const float*)d_in[2];
  const float* qcov = (const float*)d_in[3];
  const float* Z    = (const float*)d_in[4];
  const float* sfp  = (const float*)d_in[5];
  const float* nvp  = (const float*)d_in[6];
  float* ws  = (float*)d_ws;
  float* out = (float*)d_out;

  hipMemsetAsync(d_ws, 0, 64, stream);   // zero barrier counters (capturable)
  vdmgp_k1<<<9, 256, 0, stream>>>(X, Y, qmu, qcov, Z, ws);
  vdmgp_k2<<<265, 256, 0, stream>>>(Z, sfp, nvp, ws, out);
}

// Round 10
// 66.729 us; speedup vs baseline: 1.2384x; 1.1060x over previous
//
#include <hip/hip_runtime.h>
#include <math.h>

namespace {
constexpr int N_ = 2048;
constexpr int D_ = 128;
constexpr int K_ = 8;
constexpr int M_ = 64;
constexpr float JIT = 1e-5f;
constexpr float L2E = 1.4426950408889634f;
constexpr float LN2 = 0.6931471805599453f;

// ws float offsets (bar: 4 ints at ws[0..4), zeroed by K1 block 0)
constexpr int OFF_ARR2 = 16;                    // N*16 : per-n [a[8], ib2s[8]]
constexpr int OFF_C2   = OFF_ARR2 + N_ * 16;    // N
constexpr int OFF_ARR1 = OFF_C2 + N_;           // N*16 : per-n [a[8], ib1s[8]]
constexpr int OFF_CY   = OFF_ARR1 + N_ * 16;    // N
constexpr int OFF_P2P  = OFF_CY + N_;           // 16*4096 psi2 partials
constexpr int OFF_P1Y  = OFF_P2P + 16 * 4096;   // 8*64
constexpr int OFF_PSI2 = OFF_P1Y + 512;         // 4096 reduced psi2 (left folded)
}

struct F8 { float f[8]; };

__device__ __forceinline__ float f4e(float4 v, int e) {
  return (e == 0) ? v.x : (e == 1) ? v.y : (e == 2) ? v.z : v.w;
}

// ---- barrier primitives ----------------------------------------------------
__device__ __forceinline__ void bar_arrive(int* c) {
  __syncthreads();
  if (threadIdx.x == 0) { __threadfence(); atomicAdd(c, 1); }
}
__device__ __forceinline__ void bar_wait(int* c, int target) {
  if (threadIdx.x == 0) {
    while (__hip_atomic_load(c, __ATOMIC_RELAXED, __HIP_MEMORY_SCOPE_AGENT) < target)
      __builtin_amdgcn_s_sleep(16);
    __threadfence();
  }
  __syncthreads();
}
// wave-local wait (no __syncthreads; used inside the tail block by one wave)
__device__ __forceinline__ void wave_wait(int* c, int target) {
  while (__hip_atomic_load(c, __ATOMIC_RELAXED, __HIP_MEMORY_SCOPE_AGENT) < target)
    __builtin_amdgcn_s_sleep(16);
  __threadfence();
}

// unrolled 2x2-block symmetric sweep: reg (column `lane` of SPD A) ->
// column of (-A^{-1}); returns log2(det A). rowbuf is [parity*2 + A/B][64].
__device__ __forceinline__ float sweep2x2(float* reg, float (*rowbuf)[M_], int lane) {
  float ld = 0.f;
#pragma unroll
  for (int p = 0; p < M_; p += 2) {
    const int par = (p >> 1) & 1;
    float* rbA = rowbuf[par * 2 + 0];
    float* rbB = rowbuf[par * 2 + 1];
    rbA[lane] = reg[p];
    rbB[lane] = reg[p + 1];
    float4 ra[16], rb[16];
    const float4* rbAq = reinterpret_cast<const float4*>(rbA);
    const float4* rbBq = reinterpret_cast<const float4*>(rbB);
#pragma unroll
    for (int q = 0; q < 16; q++) { ra[q] = rbAq[q]; rb[q] = rbBq[q]; }

    const float P00 = f4e(ra[p >> 2], p & 3);
    const float P01 = f4e(ra[(p + 1) >> 2], (p + 1) & 3);
    const float P11 = f4e(rb[(p + 1) >> 2], (p + 1) & 3);
    const float det = fmaf(P00, P11, -P01 * P01);
    const float idet = __builtin_amdgcn_rcpf(det);
    ld += __log2f(det);
    const float Pi00 =  P11 * idet;
    const float Pi01 = -P01 * idet;
    const float Pi11 =  P00 * idet;

    const bool isp = (lane == p), isq = (lane == p + 1);
    const float a0 = reg[p], a1 = reg[p + 1];
    const float w0 = isp ? Pi00 : (isq ? Pi01 : fmaf(Pi00, a0, Pi01 * a1));
    const float w1 = isp ? Pi01 : (isq ? Pi11 : fmaf(Pi01, a0, Pi11 * a1));
    const float t0 = isp ? (1.f - w0) : (isq ? -w0 : w0);
    const float t1 = isq ? (1.f - w1) : (isp ? -w1 : w1);
    const float f0 = (isp || isq) ? -w0 : w0;
    const float f1 = (isp || isq) ? -w1 : w1;
#pragma unroll
    for (int q = 0; q < 16; q++) {
      const float4 va = ra[q], vb = rb[q];
      reg[4 * q + 0] = fmaf(-t1, vb.x, fmaf(-t0, va.x, reg[4 * q + 0]));
      reg[4 * q + 1] = fmaf(-t1, vb.y, fmaf(-t0, va.y, reg[4 * q + 1]));
      reg[4 * q + 2] = fmaf(-t1, vb.z, fmaf(-t0, va.z, reg[4 * q + 2]));
      reg[4 * q + 3] = fmaf(-t1, vb.w, fmaf(-t0, va.w, reg[4 * q + 3]));
    }
    reg[p] = f0;
    reg[p + 1] = f1;
  }
  return ld;
}

// ---------------------------------------------------------------------------
// K1: 8 prep blocks. Block 0 also zeroes the barrier counters (runs before
// K2 in stream order, so no race).
// ---------------------------------------------------------------------------
__global__ __launch_bounds__(256) void vdmgp_k1(
    const float* __restrict__ X, const float* __restrict__ Y,
    const float* __restrict__ qmu, const float* __restrict__ qcov,
    float* __restrict__ ws) {
  __shared__ float smu[D_ * K_];   // [d][k]
  __shared__ float scov[D_ * K_];
  const int tid = threadIdx.x;
  const int b = blockIdx.x;

  if (b == 0 && tid < 4) ((int*)ws)[tid] = 0;

  for (int idx = tid; idx < K_ * D_; idx += 256) {
    int k = idx >> 7, d = idx & 127;
    smu[d * K_ + k]  = qmu[idx];
    scov[d * K_ + k] = qcov[idx];
  }
  __syncthreads();

  const int n = b * 256 + tid;
  float a[K_], s2[K_];
#pragma unroll
  for (int k = 0; k < K_; k++) { a[k] = 0.f; s2[k] = 0.f; }

  const float4* xrow = reinterpret_cast<const float4*>(X + n * D_);
#pragma unroll 2
  for (int dq = 0; dq < D_ / 4; dq++) {
    float4 xv = xrow[dq];
    float xs[4] = {xv.x, xv.y, xv.z, xv.w};
#pragma unroll
    for (int t = 0; t < 4; t++) {
      const int d = dq * 4 + t;
      const float x = xs[t];
      const float xx = x * x;
      F8 mu = *reinterpret_cast<const F8*>(&smu[d * K_]);
      F8 cv = *reinterpret_cast<const F8*>(&scov[d * K_]);
#pragma unroll
      for (int k = 0; k < K_; k++) {
        a[k]  = fmaf(mu.f[k], x, a[k]);
        s2[k] = fmaf(cv.f[k], xx, s2[k]);
      }
    }
  }

  float4 w2[4], w1[4];
  float prod2 = 1.f, prod1 = 1.f;
#pragma unroll
  for (int k = 0; k < K_; k++) {
    const float b2 = 2.f * s2[k] + 1.f;
    const float b1 = 1.f + s2[k];
    reinterpret_cast<float*>(w2)[k]     = a[k];
    reinterpret_cast<float*>(w2)[8 + k] = L2E / b2;
    reinterpret_cast<float*>(w1)[k]     = a[k];
    reinterpret_cast<float*>(w1)[8 + k] = 0.5f * L2E / b1;
    prod2 *= rsqrtf(b2);
    prod1 *= rsqrtf(b1);
  }
  float4* a2q = reinterpret_cast<float4*>(ws + OFF_ARR2 + n * 16);
  float4* a1q = reinterpret_cast<float4*>(ws + OFF_ARR1 + n * 16);
#pragma unroll
  for (int e = 0; e < 4; e++) { a2q[e] = w2[e]; a1q[e] = w1[e]; }
  (ws + OFF_C2)[n] = prod2;
  (ws + OFF_CY)[n] = prod1 * Y[n];
}

// ---------------------------------------------------------------------------
// K2: 257 blocks.
//   b==0        : tail (resident from t=0). wave0: Kuu sweep -> -Kuu^{-1} in
//                 LDS + ld1. wave1: wait reduced psi2 -> stage -> A2 sweep ->
//                 ld2+quad. wave2: YY. wave3: KL. Then trace + combine.
//   b>=1, t=b-1 : psi2 task (chunk t>>4, pairblk t&15) -> bar0.
//                 t<16 : then reduce slice t (16 spinners) -> bar2.
//                 16<=t<24 : then Psi1^T Y chunk (t-16) -> bar1.
// ---------------------------------------------------------------------------
__global__ __launch_bounds__(256) void vdmgp_k2(
    const float* __restrict__ Y,
    const float* __restrict__ qmu, const float* __restrict__ qcov,
    const float* __restrict__ Z,
    const float* __restrict__ sfp, const float* __restrict__ nvp,
    float* __restrict__ ws, float* __restrict__ out) {
  __shared__ __align__(16) float pool[9352];

  int* bar = (int*)ws;
  const int tid = threadIdx.x;
  const int b = blockIdx.x;
  const float sf = sfp[0];

  if (b > 0) {
    const int t = b - 1;
    // -------- psi2 task --------
    {
      float* sa = pool;           // 128*16
      float* sc = pool + 2048;    // 128
      const int chunk = t >> 4;
      const int nbase = chunk * 128;
      const float4* src = reinterpret_cast<const float4*>(ws + OFF_ARR2 + nbase * 16);
      float4* dst = reinterpret_cast<float4*>(sa);
      for (int idx = tid; idx < 128 * 4; idx += 256) dst[idx] = src[idx];
      if (tid < 128) sc[tid] = (ws + OFF_C2)[nbase + tid];
      __syncthreads();

      const int pair = (t & 15) * 256 + tid;
      const int i = pair >> 6, j = pair & 63;
      float zb[K_];
#pragma unroll
      for (int k = 0; k < K_; k++) zb[k] = 0.5f * (Z[i * K_ + k] + Z[j * K_ + k]);

      float acc = 0.f;
      for (int nl = 0; nl < 128; nl++) {
        const F8 av = *reinterpret_cast<const F8*>(&sa[nl * 16]);
        const F8 ib = *reinterpret_cast<const F8*>(&sa[nl * 16 + 8]);
        float s = 0.f;
#pragma unroll
        for (int k = 0; k < K_; k++) {
          const float tt = av.f[k] - zb[k];
          s = fmaf(tt * tt, ib.f[k], s);
        }
        acc = fmaf(sc[nl], exp2f(-s), acc);
      }
      (ws + OFF_P2P)[chunk * 4096 + pair] = acc;
    }
    bar_arrive(&bar[0]);

    if (t < 16) {
      // -------- reduce slice t: pairs [256t, 256t+256) --------
      bar_wait(&bar[0], 256);
      const int p = t * 256 + tid;
      float acc = 0.f;
#pragma unroll
      for (int c = 0; c < 16; c++) acc += ws[OFF_P2P + c * 4096 + p];
      const int i = p >> 6, j = p & 63;
      float sq = 0.f;
#pragma unroll
      for (int k = 0; k < K_; k++) {
        const float dd = Z[i * K_ + k] - Z[j * K_ + k];
        sq = fmaf(dd, dd, sq);
      }
      ws[OFF_PSI2 + p] = sf * sf * exp2f(-0.25f * L2E * sq) * acc;
      bar_arrive(&bar[2]);
    } else if (t < 24) {
      // -------- Psi1^T Y chunk (t-16) --------
      float* sa1 = pool;          // 256*16
      float* scy = pool + 4096;   // 256
      float* red = pool + 4352;   // 256
      const int chunk = t - 16;
      const int nbase = chunk * 256;
      const float4* src = reinterpret_cast<const float4*>(ws + OFF_ARR1 + nbase * 16);
      float4* dst = reinterpret_cast<float4*>(sa1);
#pragma unroll
      for (int r = 0; r < 4; r++) dst[r * 256 + tid] = src[r * 256 + tid];
      scy[tid] = (ws + OFF_CY)[nbase + tid];
      __syncthreads();

      const int m = tid & 63;
      const int stripe = tid >> 6;
      float zm[K_];
#pragma unroll
      for (int k = 0; k < K_; k++) zm[k] = Z[m * K_ + k];

      float acc = 0.f;
      for (int u = 0; u < 64; u++) {
        const int nl = stripe * 64 + u;
        const F8 av = *reinterpret_cast<const F8*>(&sa1[nl * 16]);
        const F8 ib = *reinterpret_cast<const F8*>(&sa1[nl * 16 + 8]);
        float s = 0.f;
#pragma unroll
        for (int k = 0; k < K_; k++) {
          const float d = av.f[k] - zm[k];
          s = fmaf(d * d, ib.f[k], s);
        }
        acc = fmaf(scy[nl], exp2f(-s), acc);
      }
      red[tid] = acc;
      __syncthreads();
      if (tid < 64)
        (ws + OFF_P1Y)[chunk * 64 + tid] =
            red[tid] + red[64 + tid] + red[128 + tid] + red[192 + tid];
      bar_arrive(&bar[1]);
    }
    return;
  }

  // -------- b == 0: tail --------
  float (*P2s)[M_]    = reinterpret_cast<float(*)[M_]>(pool);         // 4096
  float (*kui)[M_]    = reinterpret_cast<float(*)[M_]>(pool + 4096);  // 4096
  float (*zl)[9]      = reinterpret_cast<float(*)[9]>(pool + 8192);   // 576
  float (*rowbuf0)[M_] = reinterpret_cast<float(*)[M_]>(pool + 8768); // 256
  float (*rowbuf1)[M_] = reinterpret_cast<float(*)[M_]>(pool + 9024); // 256
  float* pysL  = pool + 9280;                                         // 64
  float* scalL = pool + 9344;                                         // 8

  for (int idx = tid; idx < M_ * K_; idx += 256) zl[idx >> 3][idx & 7] = Z[idx];
  __syncthreads();   // S1

  const int lane = tid & 63;
  const int wave = tid >> 6;
  const float s2v = nvp[0];

  if (wave == 0) {
    // Kuu^{-1} sweep (independent of workers; starts at t=0)
    float zj[K_];
#pragma unroll
    for (int k = 0; k < K_; k++) zj[k] = zl[lane][k];
    float reg[M_];
#pragma unroll
    for (int i = 0; i < M_; i++) {
      float sq = 0.f;
#pragma unroll
      for (int k = 0; k < K_; k++) { const float dd = zl[i][k] - zj[k]; sq = fmaf(dd, dd, sq); }
      reg[i] = exp2f(-0.5f * L2E * sq) + ((i == lane) ? JIT : 0.f);
    }
    const float ld1 = sweep2x2(reg, rowbuf0, lane);
#pragma unroll
    for (int i = 0; i < M_; i++) kui[i][lane] = reg[i];   // -Kuu^{-1}
    if (lane == 0) scalL[2] = LN2 * ld1;
  } else if (wave == 1) {
    // wait for reduced psi2, stage, build A2, sweep
    wave_wait(&bar[2], 16);
    const float4* srcq = reinterpret_cast<const float4*>(ws + OFF_PSI2);
    float4* dstq = reinterpret_cast<float4*>(&P2s[0][0]);
#pragma unroll
    for (int q = 0; q < 16; q++) dstq[q * 64 + lane] = srcq[q * 64 + lane];
    wave_wait(&bar[1], 8);
    {
      float s = 0.f;
#pragma unroll
      for (int c = 0; c < 8; c++) s += ws[OFF_P1Y + c * M_ + lane];
      pysL[lane] = sf * s;
    }
    float zj[K_];
#pragma unroll
    for (int k = 0; k < K_; k++) zj[k] = zl[lane][k];
    float reg[M_];
#pragma unroll
    for (int i = 0; i < M_; i++) {
      float sq = 0.f;
#pragma unroll
      for (int k = 0; k < K_; k++) { const float dd = zl[i][k] - zj[k]; sq = fmaf(dd, dd, sq); }
      const float jit = (i == lane) ? JIT : 0.f;
      const float kj = exp2f(-0.5f * L2E * sq) + jit;
      reg[i] = fmaf(s2v, kj, P2s[i][lane] + jit);
    }
    const float ld2 = sweep2x2(reg, rowbuf1, lane);
    float local = 0.f;
#pragma unroll
    for (int i = 0; i < M_; i++) local = fmaf(reg[i], pysL[i], local);
    local *= pysL[lane];
#pragma unroll
    for (int off = 32; off > 0; off >>= 1) local += __shfl_down(local, off, 64);
    if (lane == 0) { scalL[6] = LN2 * ld2; scalL[7] = -local; }
  } else if (wave == 2) {
    float yy = 0.f;
#pragma unroll
    for (int u = 0; u < 32; u++) {
      const float y = Y[u * 64 + lane];
      yy = fmaf(y, y, yy);
    }
#pragma unroll
    for (int off = 32; off > 0; off >>= 1) yy += __shfl_down(yy, off, 64);
    if (lane == 0) scalL[0] = yy;
  } else {
    const int k = lane >> 3;
    const int d0 = (lane & 7) * 16;
    float slog = 0.f, srow = 0.f;
#pragma unroll
    for (int u = 0; u < 16; u++) {
      const float qc = qcov[k * D_ + d0 + u];
      const float qm = qmu[k * D_ + d0 + u];
      slog += logf(qc);
      srow += qc + qm * qm;
    }
#pragma unroll
    for (int off = 4; off > 0; off >>= 1) {
      slog += __shfl_down(slog, off, 8);
      srow += __shfl_down(srow, off, 8);
    }
    float klr = ((lane & 7) == 0)
        ? (slog - (float)D_ * logf(srow) + (float)D_ * logf((float)D_)) : 0.f;
    klr += __shfl_down(klr, 32, 64);
    klr += __shfl_down(klr, 16, 64);
    klr += __shfl_down(klr, 8, 64);
    if (lane == 0) scalL[1] = klr;
  }
  __syncthreads();   // S2: kui (wave0) and P2s (wave1) both visible

  if (wave == 0) {
    float acc = 0.f;
#pragma unroll
    for (int i = 0; i < M_; i++) acc = fmaf(kui[i][lane], P2s[i][lane], acc);
#pragma unroll
    for (int off = 32; off > 0; off >>= 1) acc += __shfl_down(acc, off, 64);
    if (lane == 0) scalL[5] = -acc;   // trace
  }
  __syncthreads();   // S3

  if (tid == 0) {
    const float YY = scalL[0], KL = scalL[1], ld1 = scalL[2];
    const float tr = scalL[5], ld2 = scalL[6], quad = scalL[7];
    const float inv = 1.0f / s2v;
    const float F1 = -(float)N_ * 1.8378770664093453f
                   - (float)(N_ - M_) * logf(s2v)
                   + (ld1 - ld2)
                   - YY * inv
                   + quad * inv
                   - (float)N_ * sf * sf * inv
                   + tr * inv;
    out[0] = 0.5f * (F1 + KL);
  }
}

extern "C" void kernel_launch(void* const* d_in, const int* in_sizes, int n_in,
                              void* d_out, int out_size, void* d_ws, size_t ws_size,
                              hipStream_t stream) {
  const float* X    = (const float*)d_in[0];
  const float* Y    = (const float*)d_in[1];
  const float* qmu  = (const float*)d_in[2];
  const float* qcov = (const float*)d_in[3];
  const float* Z    = (const float*)d_in[4];
  const float* sfp  = (const float*)d_in[5];
  const float* nvp  = (const float*)d_in[6];
  float* ws  = (float*)d_ws;
  float* out = (float*)d_out;

  vdmgp_k1<<<8, 256, 0, stream>>>(X, Y, qmu, qcov, ws);
  vdmgp_k2<<<257, 256, 0, stream>>>(Y, qmu, qcov, Z, sfp, nvp, ws, out);
}

// Round 11
// 52.512 us; speedup vs baseline: 1.5736x; 1.2707x over previous
//
#include <hip/hip_runtime.h>
#include <math.h>

namespace {
constexpr int N_ = 2048;
constexpr int D_ = 128;
constexpr int K_ = 8;
constexpr int M_ = 64;
constexpr float JIT = 1e-5f;
constexpr float L2E = 1.4426950408889634f;
constexpr float LN2 = 0.6931471805599453f;

// ws float offsets (bar: 4 ints at ws[0..4), zeroed by K1 block 0)
constexpr int OFF_ARR2 = 16;                    // N*16 : per-n [a[8], ib2s[8]]
constexpr int OFF_C2   = OFF_ARR2 + N_ * 16;    // N
constexpr int OFF_ARR1 = OFF_C2 + N_;           // N*16 : per-n [a[8], ib1s[8]]
constexpr int OFF_CY   = OFF_ARR1 + N_ * 16;    // N
constexpr int OFF_P2P  = OFF_CY + N_;           // 16*4096 psi2 partials
constexpr int OFF_P1Y  = OFF_P2P + 16 * 4096;   // 8*64
constexpr int OFF_PSI2 = OFF_P1Y + 512;         // 4096 reduced psi2 (left folded)
constexpr int OFF_KUI  = OFF_PSI2 + 4096;       // 4096 : -Kuu^{-1}
constexpr int OFF_SC   = OFF_KUI + 4096;        // 3 : YY, KL, log2det(Kuu)
}

struct F8 { float f[8]; };

// ---- barrier primitives ----------------------------------------------------
__device__ __forceinline__ void bar_arrive(int* c) {
  __syncthreads();
  if (threadIdx.x == 0) { __threadfence(); atomicAdd(c, 1); }
}
__device__ __forceinline__ void bar_wait(int* c, int target) {
  if (threadIdx.x == 0) {
    while (__hip_atomic_load(c, __ATOMIC_RELAXED, __HIP_MEMORY_SCOPE_AGENT) < target)
      __builtin_amdgcn_s_sleep(16);
    __threadfence();
  }
  __syncthreads();
}

// ---------------------------------------------------------------------------
// 4-wave 2x2-block symmetric sweep over a 64x64 SPD matrix distributed as
//   reg[r] = A[16*wave + r][lane]   (thread = (wave, lane), 256 threads)
// After 32 steps: reg[r] = (-A^{-1})[16*wave + r][lane].
// Returns log2(det A), valid in EVERY thread (all compute identical dets).
// rowbuf[parity][A/B][64] double-buffered; one __syncthreads per step (the
// parity alternation makes the WAR on rowbuf safe with a single sync).
// Lane formulas copied verbatim from the verified 1-wave sweep (absmax 0.0).
// ---------------------------------------------------------------------------
__device__ __forceinline__ float sweep2x2_w4(
    float* reg, float (*rowbuf)[2][M_], int wave, int lane) {
  float ld = 0.f;
#pragma unroll
  for (int p = 0; p < M_; p += 2) {
    const int par = (p >> 1) & 1;
    float* rbA = rowbuf[par][0];
    float* rbB = rowbuf[par][1];
    const int rp = p & 15;
    if (wave == (p >> 4)) {
      rbA[lane] = reg[rp];          // row p   across lanes (symmetry)
      rbB[lane] = reg[rp + 1];      // row p+1
    }
    __syncthreads();

    const float P00 = rbA[p];
    const float P01 = rbA[p + 1];
    const float P11 = rbB[p + 1];
    const float a0  = rbA[lane];    // = A[p][lane]
    const float a1  = rbB[lane];    // = A[p+1][lane]
    const float det = fmaf(P00, P11, -P01 * P01);
    const float idet = __builtin_amdgcn_rcpf(det);
    ld += __log2f(det);
    const float Pi00 =  P11 * idet;
    const float Pi01 = -P01 * idet;
    const float Pi11 =  P00 * idet;

    const bool isp = (lane == p), isq = (lane == p + 1);
    const float w0 = isp ? Pi00 : (isq ? Pi01 : fmaf(Pi00, a0, Pi01 * a1));
    const float w1 = isp ? Pi01 : (isq ? Pi11 : fmaf(Pi01, a0, Pi11 * a1));
    const float t0 = isp ? (1.f - w0) : (isq ? -w0 : w0);
    const float t1 = isq ? (1.f - w1) : (isp ? -w1 : w1);
    const float f0 = (isp || isq) ? -w0 : w0;
    const float f1 = (isp || isq) ? -w1 : w1;

    // update this wave's 16-row window (broadcast float4 reads)
    const float4* rAq = reinterpret_cast<const float4*>(rbA + 16 * wave);
    const float4* rBq = reinterpret_cast<const float4*>(rbB + 16 * wave);
#pragma unroll
    for (int q = 0; q < 4; q++) {
      const float4 va = rAq[q], vb = rBq[q];
      reg[4 * q + 0] = fmaf(-t1, vb.x, fmaf(-t0, va.x, reg[4 * q + 0]));
      reg[4 * q + 1] = fmaf(-t1, vb.y, fmaf(-t0, va.y, reg[4 * q + 1]));
      reg[4 * q + 2] = fmaf(-t1, vb.z, fmaf(-t0, va.z, reg[4 * q + 2]));
      reg[4 * q + 3] = fmaf(-t1, vb.w, fmaf(-t0, va.w, reg[4 * q + 3]));
    }
    if (wave == (p >> 4)) {
      reg[rp]     = f0;
      reg[rp + 1] = f1;
    }
  }
  return ld;
}

// ---------------------------------------------------------------------------
// K1: 10 blocks. b<8: prep. b==8: 4-wave Kuu^{-1} sweep -> ws. b==9: YY + KL.
// Block 0 zeroes the barrier counters (K2 is stream-ordered after K1).
// ---------------------------------------------------------------------------
__global__ __launch_bounds__(256) void vdmgp_k1(
    const float* __restrict__ X, const float* __restrict__ Y,
    const float* __restrict__ qmu, const float* __restrict__ qcov,
    const float* __restrict__ Z, float* __restrict__ ws) {
  __shared__ float smu[D_ * K_];   // [d][k]
  __shared__ float scov[D_ * K_];
  __shared__ float zl[M_][9];
  __shared__ __align__(16) float rowbuf[2][2][M_];
  const int tid = threadIdx.x;
  const int b = blockIdx.x;

  if (b == 0 && tid < 4) ((int*)ws)[tid] = 0;

  if (b == 8) {
    // 4-wave Kuu^{-1} sweep
    for (int idx = tid; idx < M_ * K_; idx += 256) zl[idx >> 3][idx & 7] = Z[idx];
    __syncthreads();
    const int lane = tid & 63;
    const int wave = tid >> 6;
    float zj[K_];
#pragma unroll
    for (int k = 0; k < K_; k++) zj[k] = zl[lane][k];
    float reg[16];
#pragma unroll
    for (int r = 0; r < 16; r++) {
      const int gi = 16 * wave + r;
      float sq = 0.f;
#pragma unroll
      for (int k = 0; k < K_; k++) { const float dd = zl[gi][k] - zj[k]; sq = fmaf(dd, dd, sq); }
      reg[r] = exp2f(-0.5f * L2E * sq) + ((gi == lane) ? JIT : 0.f);
    }
    const float ld1 = sweep2x2_w4(reg, rowbuf, wave, lane);
#pragma unroll
    for (int r = 0; r < 16; r++)
      ws[OFF_KUI + (16 * wave + r) * 64 + lane] = reg[r];   // -Kuu^{-1}
    if (tid == 0) ws[OFF_SC + 2] = LN2 * ld1;
    return;
  }

  if (b == 9) {
    const int lane = tid & 63;
    const int wave = tid >> 6;
    if (wave == 0) {
      float yy = 0.f;
#pragma unroll
      for (int t = 0; t < 32; t++) {
        const float y = Y[t * 64 + lane];
        yy = fmaf(y, y, yy);
      }
#pragma unroll
      for (int off = 32; off > 0; off >>= 1) yy += __shfl_down(yy, off, 64);
      if (lane == 0) ws[OFF_SC + 0] = yy;
    } else if (wave == 1) {
      const int k = lane >> 3;
      const int d0 = (lane & 7) * 16;
      float slog = 0.f, srow = 0.f;
#pragma unroll
      for (int t = 0; t < 16; t++) {
        const float qc = qcov[k * D_ + d0 + t];
        const float qm = qmu[k * D_ + d0 + t];
        slog += logf(qc);
        srow += qc + qm * qm;
      }
#pragma unroll
      for (int off = 4; off > 0; off >>= 1) {
        slog += __shfl_down(slog, off, 8);
        srow += __shfl_down(srow, off, 8);
      }
      float klr = ((lane & 7) == 0)
          ? (slog - (float)D_ * logf(srow) + (float)D_ * logf((float)D_)) : 0.f;
      klr += __shfl_down(klr, 32, 64);
      klr += __shfl_down(klr, 16, 64);
      klr += __shfl_down(klr, 8, 64);
      if (lane == 0) ws[OFF_SC + 1] = klr;
    }
    return;
  }

  // prep: one n per thread
  for (int idx = tid; idx < K_ * D_; idx += 256) {
    int k = idx >> 7, d = idx & 127;
    smu[d * K_ + k]  = qmu[idx];
    scov[d * K_ + k] = qcov[idx];
  }
  __syncthreads();

  const int n = b * 256 + tid;
  float a[K_], s2[K_];
#pragma unroll
  for (int k = 0; k < K_; k++) { a[k] = 0.f; s2[k] = 0.f; }

  const float4* xrow = reinterpret_cast<const float4*>(X + n * D_);
#pragma unroll 2
  for (int dq = 0; dq < D_ / 4; dq++) {
    float4 xv = xrow[dq];
    float xs[4] = {xv.x, xv.y, xv.z, xv.w};
#pragma unroll
    for (int t = 0; t < 4; t++) {
      const int d = dq * 4 + t;
      const float x = xs[t];
      const float xx = x * x;
      F8 mu = *reinterpret_cast<const F8*>(&smu[d * K_]);
      F8 cv = *reinterpret_cast<const F8*>(&scov[d * K_]);
#pragma unroll
      for (int k = 0; k < K_; k++) {
        a[k]  = fmaf(mu.f[k], x, a[k]);
        s2[k] = fmaf(cv.f[k], xx, s2[k]);
      }
    }
  }

  float4 w2[4], w1[4];
  float prod2 = 1.f, prod1 = 1.f;
#pragma unroll
  for (int k = 0; k < K_; k++) {
    const float b2 = 2.f * s2[k] + 1.f;
    const float b1 = 1.f + s2[k];
    reinterpret_cast<float*>(w2)[k]     = a[k];
    reinterpret_cast<float*>(w2)[8 + k] = L2E / b2;
    reinterpret_cast<float*>(w1)[k]     = a[k];
    reinterpret_cast<float*>(w1)[8 + k] = 0.5f * L2E / b1;
    prod2 *= rsqrtf(b2);
    prod1 *= rsqrtf(b1);
  }
  float4* a2q = reinterpret_cast<float4*>(ws + OFF_ARR2 + n * 16);
  float4* a1q = reinterpret_cast<float4*>(ws + OFF_ARR1 + n * 16);
#pragma unroll
  for (int e = 0; e < 4; e++) { a2q[e] = w2[e]; a1q[e] = w1[e]; }
  (ws + OFF_C2)[n] = prod2;
  (ws + OFF_CY)[n] = prod1 * Y[n];
}

// ---------------------------------------------------------------------------
// K2: 257 blocks.
//   b==0        : tail. wait reduced psi2 -> stage -> 4-wave A2 sweep ->
//                 quad + trace block-reduce -> combine -> out[0].
//   b>=1, t=b-1 : psi2 task (chunk t>>4, pairblk t&15) -> bar0.
//                 t<16 : then reduce slice t -> bar2.
//                 16<=t<24 : then Psi1^T Y chunk (t-16) -> bar1.
// ---------------------------------------------------------------------------
__global__ __launch_bounds__(256) void vdmgp_k2(
    const float* __restrict__ Z,
    const float* __restrict__ sfp, const float* __restrict__ nvp,
    float* __restrict__ ws, float* __restrict__ out) {
  __shared__ __align__(16) float pool[5520];

  int* bar = (int*)ws;
  const int tid = threadIdx.x;
  const int b = blockIdx.x;
  const float sf = sfp[0];

  if (b > 0) {
    const int t = b - 1;
    // -------- psi2 task --------
    {
      float* sa = pool;           // 128*16
      float* sc = pool + 2048;    // 128
      const int chunk = t >> 4;
      const int nbase = chunk * 128;
      const float4* src = reinterpret_cast<const float4*>(ws + OFF_ARR2 + nbase * 16);
      float4* dst = reinterpret_cast<float4*>(sa);
      for (int idx = tid; idx < 128 * 4; idx += 256) dst[idx] = src[idx];
      if (tid < 128) sc[tid] = (ws + OFF_C2)[nbase + tid];
      __syncthreads();

      const int pair = (t & 15) * 256 + tid;
      const int i = pair >> 6, j = pair & 63;
      float zb[K_];
#pragma unroll
      for (int k = 0; k < K_; k++) zb[k] = 0.5f * (Z[i * K_ + k] + Z[j * K_ + k]);

      float acc = 0.f;
      for (int nl = 0; nl < 128; nl++) {
        const F8 av = *reinterpret_cast<const F8*>(&sa[nl * 16]);
        const F8 ib = *reinterpret_cast<const F8*>(&sa[nl * 16 + 8]);
        float s = 0.f;
#pragma unroll
        for (int k = 0; k < K_; k++) {
          const float tt = av.f[k] - zb[k];
          s = fmaf(tt * tt, ib.f[k], s);
        }
        acc = fmaf(sc[nl], exp2f(-s), acc);
      }
      (ws + OFF_P2P)[chunk * 4096 + pair] = acc;
    }
    bar_arrive(&bar[0]);

    if (t < 16) {
      // -------- reduce slice t: pairs [256t, 256t+256) --------
      bar_wait(&bar[0], 256);
      const int p = t * 256 + tid;
      float acc = 0.f;
#pragma unroll
      for (int c = 0; c < 16; c++) acc += ws[OFF_P2P + c * 4096 + p];
      const int i = p >> 6, j = p & 63;
      float sq = 0.f;
#pragma unroll
      for (int k = 0; k < K_; k++) {
        const float dd = Z[i * K_ + k] - Z[j * K_ + k];
        sq = fmaf(dd, dd, sq);
      }
      ws[OFF_PSI2 + p] = sf * sf * exp2f(-0.25f * L2E * sq) * acc;
      bar_arrive(&bar[2]);
    } else if (t < 24) {
      // -------- Psi1^T Y chunk (t-16) --------
      float* sa1 = pool;          // 256*16
      float* scy = pool + 4096;   // 256
      float* red = pool + 4352;   // 256
      const int chunk = t - 16;
      const int nbase = chunk * 256;
      const float4* src = reinterpret_cast<const float4*>(ws + OFF_ARR1 + nbase * 16);
      float4* dst = reinterpret_cast<float4*>(sa1);
#pragma unroll
      for (int r = 0; r < 4; r++) dst[r * 256 + tid] = src[r * 256 + tid];
      scy[tid] = (ws + OFF_CY)[nbase + tid];
      __syncthreads();

      const int m = tid & 63;
      const int stripe = tid >> 6;
      float zm[K_];
#pragma unroll
      for (int k = 0; k < K_; k++) zm[k] = Z[m * K_ + k];

      float acc = 0.f;
      for (int u = 0; u < 64; u++) {
        const int nl = stripe * 64 + u;
        const F8 av = *reinterpret_cast<const F8*>(&sa1[nl * 16]);
        const F8 ib = *reinterpret_cast<const F8*>(&sa1[nl * 16 + 8]);
        float s = 0.f;
#pragma unroll
        for (int k = 0; k < K_; k++) {
          const float d = av.f[k] - zm[k];
          s = fmaf(d * d, ib.f[k], s);
        }
        acc = fmaf(scy[nl], exp2f(-s), acc);
      }
      red[tid] = acc;
      __syncthreads();
      if (tid < 64)
        (ws + OFF_P1Y)[chunk * 64 + tid] =
            red[tid] + red[64 + tid] + red[128 + tid] + red[192 + tid];
      bar_arrive(&bar[1]);
    }
    return;
  }

  // -------- b == 0: tail --------
  float (*P2s)[M_]       = reinterpret_cast<float(*)[M_]>(pool);          // 4096
  float (*zl)[9]         = reinterpret_cast<float(*)[9]>(pool + 4096);    // 576
  float (*rowbuf)[2][M_] = reinterpret_cast<float(*)[2][M_]>(pool + 4672);// 256
  float* pysL  = pool + 4928;                                             // 64
  float* scalL = pool + 4992;                                             // 8
  float* redQ  = pool + 5000;                                             // 256
  float* redT  = pool + 5256;                                             // 256

  const int lane = tid & 63;
  const int wave = tid >> 6;
  const float s2v = nvp[0];

  for (int idx = tid; idx < M_ * K_; idx += 256) zl[idx >> 3][idx & 7] = Z[idx];

  bar_wait(&bar[2], 16);    // reduced psi2 ready (implies bar0 done)
  {
    const float4* srcq = reinterpret_cast<const float4*>(ws + OFF_PSI2);
    float4* dstq = reinterpret_cast<float4*>(&P2s[0][0]);
#pragma unroll
    for (int q = 0; q < 4; q++) dstq[q * 256 + tid] = srcq[q * 256 + tid];
  }
  bar_wait(&bar[1], 8);     // p1y ready
  if (tid < M_) {
    float s = 0.f;
#pragma unroll
    for (int c = 0; c < 8; c++) s += ws[OFF_P1Y + c * M_ + tid];
    pysL[tid] = sf * s;
  }
  __syncthreads();

  // build A2 rows [16w,16w+16) of column `lane`
  float zj[K_];
#pragma unroll
  for (int k = 0; k < K_; k++) zj[k] = zl[lane][k];
  float reg[16];
#pragma unroll
  for (int r = 0; r < 16; r++) {
    const int gi = 16 * wave + r;
    float sq = 0.f;
#pragma unroll
    for (int k = 0; k < K_; k++) { const float dd = zl[gi][k] - zj[k]; sq = fmaf(dd, dd, sq); }
    const float jit = (gi == lane) ? JIT : 0.f;
    const float kj = exp2f(-0.5f * L2E * sq) + jit;
    reg[r] = fmaf(s2v, kj, P2s[gi][lane] + jit);
  }

  const float ld2 = sweep2x2_w4(reg, rowbuf, wave, lane);

  // partials: quad (per-column over this wave's rows) and trace
  float sQ = 0.f, sT = 0.f;
  const float* kui = ws + OFF_KUI;
#pragma unroll
  for (int r = 0; r < 16; r++) {
    const int gi = 16 * wave + r;
    sQ = fmaf(reg[r], pysL[gi], sQ);
    sT = fmaf(kui[gi * 64 + lane], P2s[gi][lane], sT);
  }
  redQ[tid] = sQ;
  redT[tid] = sT;
  if (tid == 0) scalL[6] = LN2 * ld2;
  __syncthreads();

  if (wave == 0) {
    // quad: sum waves per column, * pys[lane], reduce over lanes
    float c = redQ[lane] + redQ[64 + lane] + redQ[128 + lane] + redQ[192 + lane];
    float q = c * pysL[lane];
#pragma unroll
    for (int off = 32; off > 0; off >>= 1) q += __shfl_down(q, off, 64);
    if (lane == 0) scalL[7] = -q;
  } else if (wave == 1) {
    float s = redT[lane] + redT[64 + lane] + redT[128 + lane] + redT[192 + lane];
#pragma unroll
    for (int off = 32; off > 0; off >>= 1) s += __shfl_down(s, off, 64);
    if (lane == 0) scalL[5] = -s;   // trace
  }
  __syncthreads();

  if (tid == 0) {
    const float YY  = ws[OFF_SC + 0];
    const float KL  = ws[OFF_SC + 1];
    const float ld1 = ws[OFF_SC + 2];
    const float tr = scalL[5], ld2v = scalL[6], quad = scalL[7];
    const float inv = 1.0f / s2v;
    const float F1 = -(float)N_ * 1.8378770664093453f
                   - (float)(N_ - M_) * logf(s2v)
                   + (ld1 - ld2v)
                   - YY * inv
                   + quad * inv
                   - (float)N_ * sf * sf * inv
                   + tr * inv;
    out[0] = 0.5f * (F1 + KL);
  }
}

extern "C" void kernel_launch(void* const* d_in, const int* in_sizes, int n_in,
                              void* d_out, int out_size, void* d_ws, size_t ws_size,
                              hipStream_t stream) {
  const float* X    = (const float*)d_in[0];
  const float* Y    = (const float*)d_in[1];
  const float* qmu  = (const float*)d_in[2];
  const float* qcov = (const float*)d_in[3];
  const float* Z    = (const float*)d_in[4];
  const float* sfp  = (const float*)d_in[5];
  const float* nvp  = (const float*)d_in[6];
  float* ws  = (float*)d_ws;
  float* out = (float*)d_out;

  vdmgp_k1<<<10, 256, 0, stream>>>(X, Y, qmu, qcov, Z, ws);
  vdmgp_k2<<<257, 256, 0, stream>>>(Z, sfp, nvp, ws, out);
}

// Round 12
// 50.143 us; speedup vs baseline: 1.6480x; 1.0472x over previous
//
#include <hip/hip_runtime.h>
#include <math.h>

namespace {
constexpr int N_ = 2048;
constexpr int D_ = 128;
constexpr int K_ = 8;
constexpr int M_ = 64;
constexpr float JIT = 1e-5f;
constexpr float L2E = 1.4426950408889634f;
constexpr float LN2 = 0.6931471805599453f;

// ws float offsets. bar region: 32 ints at ws[0..32), zeroed by K1 block 0.
//   bar[s], s in [0,16) : per-pair-slice psi2 arrival counters (target 16)
//   bar[16]             : p1y arrivals (target 8)
//   bar[17]             : reduced-psi2 slice arrivals (target 16)
constexpr int OFF_ARR2 = 32;                    // N*16 : per-n [a[8], ib2s[8]]
constexpr int OFF_C2   = OFF_ARR2 + N_ * 16;    // N
constexpr int OFF_ARR1 = OFF_C2 + N_;           // N*16 : per-n [a[8], ib1s[8]]
constexpr int OFF_CY   = OFF_ARR1 + N_ * 16;    // N
constexpr int OFF_P2P  = OFF_CY + N_;           // 16*4096 psi2 partials
constexpr int OFF_P1Y  = OFF_P2P + 16 * 4096;   // 8*64
constexpr int OFF_PSI2 = OFF_P1Y + 512;         // 4096 reduced psi2 (left folded)
constexpr int OFF_KUI  = OFF_PSI2 + 4096;       // 4096 : -Kuu^{-1}
constexpr int OFF_SC   = OFF_KUI + 4096;        // 3 : YY, KL, log2det(Kuu)
}

struct F8 { float f[8]; };

// ---- barrier primitives ----------------------------------------------------
__device__ __forceinline__ void bar_arrive(int* c) {
  __syncthreads();
  if (threadIdx.x == 0) { __threadfence(); atomicAdd(c, 1); }
}
template <int SLP>
__device__ __forceinline__ void bar_wait(int* c, int target) {
  if (threadIdx.x == 0) {
    while (__hip_atomic_load(c, __ATOMIC_RELAXED, __HIP_MEMORY_SCOPE_AGENT) < target)
      __builtin_amdgcn_s_sleep(SLP);
    __threadfence();
  }
  __syncthreads();
}

// ---------------------------------------------------------------------------
// 4-wave software-pipelined 2x2-block symmetric sweep.
//   reg[r] = A[16*wave + r][lane]  ->  (-A^{-1})[16*wave + r][lane]
// Step s's owner-of-next-pivot publishes rows p+2,p+3 (already updated) into
// the opposite parity buffer DURING step s, so step s+1 never waits on a
// fresh ds_write. One __syncthreads per step; parity double-buffer makes the
// WAR safe (all reads of buf[par^1] finished at end-of-(s-1) sync).
// Returns log2(det A), identical in every thread.
// ---------------------------------------------------------------------------
__device__ __forceinline__ float sweep2x2_pipe(
    float* reg, float (*rowbuf)[2][M_], int wave, int lane) {
  if (wave == 0) {                       // prologue: rows 0,1 (original A)
    rowbuf[0][0][lane] = reg[0];
    rowbuf[0][1][lane] = reg[1];
  }
  __syncthreads();
  float ld = 0.f;
#pragma unroll
  for (int s = 0; s < 32; ++s) {
    const int p = 2 * s;
    const int par = s & 1;
    float* rbA = rowbuf[par][0];
    float* rbB = rowbuf[par][1];
    const int own_s  = s >> 3;
    const int own_s1 = (s + 1) >> 3;
    const int rp  = p & 15;
    const int rp2 = (p + 2) & 15;

    const float P00 = rbA[p];
    const float P01 = rbA[p + 1];
    const float P11 = rbB[p + 1];
    const float a0  = rbA[lane];
    const float a1  = rbB[lane];
    const float det = fmaf(P00, P11, -P01 * P01);
    const float idet = __builtin_amdgcn_rcpf(det);
    ld += __log2f(det);
    const float Pi00 =  P11 * idet;
    const float Pi01 = -P01 * idet;
    const float Pi11 =  P00 * idet;

    const bool isp = (lane == p), isq = (lane == p + 1);
    const float w0 = isp ? Pi00 : (isq ? Pi01 : fmaf(Pi00, a0, Pi01 * a1));
    const float w1 = isp ? Pi01 : (isq ? Pi11 : fmaf(Pi01, a0, Pi11 * a1));
    const float t0 = isp ? (1.f - w0) : (isq ? -w0 : w0);
    const float t1 = isq ? (1.f - w1) : (isp ? -w1 : w1);
    const float f0 = (isp || isq) ? -w0 : w0;
    const float f1 = (isp || isq) ? -w1 : w1;

    // early-publish next step's pivot rows (same value the main loop will
    // recompute for these regs — publish-only, no restore needed)
    if (s < 31 && wave == own_s1) {
      const float e0 = fmaf(-t1, rbB[p + 2], fmaf(-t0, rbA[p + 2], reg[rp2]));
      const float e1 = fmaf(-t1, rbB[p + 3], fmaf(-t0, rbA[p + 3], reg[rp2 + 1]));
      rowbuf[par ^ 1][0][lane] = e0;
      rowbuf[par ^ 1][1][lane] = e1;
    }

    const float4* rAq = reinterpret_cast<const float4*>(rbA + 16 * wave);
    const float4* rBq = reinterpret_cast<const float4*>(rbB + 16 * wave);
#pragma unroll
    for (int q = 0; q < 4; q++) {
      const float4 va = rAq[q], vb = rBq[q];
      reg[4 * q + 0] = fmaf(-t1, vb.x, fmaf(-t0, va.x, reg[4 * q + 0]));
      reg[4 * q + 1] = fmaf(-t1, vb.y, fmaf(-t0, va.y, reg[4 * q + 1]));
      reg[4 * q + 2] = fmaf(-t1, vb.z, fmaf(-t0, va.z, reg[4 * q + 2]));
      reg[4 * q + 3] = fmaf(-t1, vb.w, fmaf(-t0, va.w, reg[4 * q + 3]));
    }
    if (wave == own_s) { reg[rp] = f0; reg[rp + 1] = f1; }
    __syncthreads();
  }
  return ld;
}

// ---------------------------------------------------------------------------
// K1: 10 blocks. b<8: prep. b==8: Kuu^{-1} pipelined sweep. b==9: YY + KL.
// Block 0 zeroes the 32 barrier ints (K2 is stream-ordered after K1).
// ---------------------------------------------------------------------------
__global__ __launch_bounds__(256) void vdmgp_k1(
    const float* __restrict__ X, const float* __restrict__ Y,
    const float* __restrict__ qmu, const float* __restrict__ qcov,
    const float* __restrict__ Z, float* __restrict__ ws) {
  __shared__ float smu[D_ * K_];   // [d][k]
  __shared__ float scov[D_ * K_];
  __shared__ float zl[M_][9];
  __shared__ __align__(16) float rowbuf[2][2][M_];
  const int tid = threadIdx.x;
  const int b = blockIdx.x;

  if (b == 0 && tid < 32) ((int*)ws)[tid] = 0;

  if (b == 8) {
    for (int idx = tid; idx < M_ * K_; idx += 256) zl[idx >> 3][idx & 7] = Z[idx];
    __syncthreads();
    const int lane = tid & 63;
    const int wave = tid >> 6;
    float zj[K_];
#pragma unroll
    for (int k = 0; k < K_; k++) zj[k] = zl[lane][k];
    float reg[16];
#pragma unroll
    for (int r = 0; r < 16; r++) {
      const int gi = 16 * wave + r;
      float sq = 0.f;
#pragma unroll
      for (int k = 0; k < K_; k++) { const float dd = zl[gi][k] - zj[k]; sq = fmaf(dd, dd, sq); }
      reg[r] = exp2f(-0.5f * L2E * sq) + ((gi == lane) ? JIT : 0.f);
    }
    const float ld1 = sweep2x2_pipe(reg, rowbuf, wave, lane);
#pragma unroll
    for (int r = 0; r < 16; r++)
      ws[OFF_KUI + (16 * wave + r) * 64 + lane] = reg[r];   // -Kuu^{-1}
    if (tid == 0) ws[OFF_SC + 2] = LN2 * ld1;
    return;
  }

  if (b == 9) {
    const int lane = tid & 63;
    const int wave = tid >> 6;
    if (wave == 0) {
      float yy = 0.f;
#pragma unroll
      for (int t = 0; t < 32; t++) {
        const float y = Y[t * 64 + lane];
        yy = fmaf(y, y, yy);
      }
#pragma unroll
      for (int off = 32; off > 0; off >>= 1) yy += __shfl_down(yy, off, 64);
      if (lane == 0) ws[OFF_SC + 0] = yy;
    } else if (wave == 1) {
      const int k = lane >> 3;
      const int d0 = (lane & 7) * 16;
      float slog = 0.f, srow = 0.f;
#pragma unroll
      for (int t = 0; t < 16; t++) {
        const float qc = qcov[k * D_ + d0 + t];
        const float qm = qmu[k * D_ + d0 + t];
        slog += logf(qc);
        srow += qc + qm * qm;
      }
#pragma unroll
      for (int off = 4; off > 0; off >>= 1) {
        slog += __shfl_down(slog, off, 8);
        srow += __shfl_down(srow, off, 8);
      }
      float klr = ((lane & 7) == 0)
          ? (slog - (float)D_ * logf(srow) + (float)D_ * logf((float)D_)) : 0.f;
      klr += __shfl_down(klr, 32, 64);
      klr += __shfl_down(klr, 16, 64);
      klr += __shfl_down(klr, 8, 64);
      if (lane == 0) ws[OFF_SC + 1] = klr;
    }
    return;
  }

  // prep: one n per thread
  for (int idx = tid; idx < K_ * D_; idx += 256) {
    int k = idx >> 7, d = idx & 127;
    smu[d * K_ + k]  = qmu[idx];
    scov[d * K_ + k] = qcov[idx];
  }
  __syncthreads();

  const int n = b * 256 + tid;
  float a[K_], s2[K_];
#pragma unroll
  for (int k = 0; k < K_; k++) { a[k] = 0.f; s2[k] = 0.f; }

  const float4* xrow = reinterpret_cast<const float4*>(X + n * D_);
#pragma unroll 2
  for (int dq = 0; dq < D_ / 4; dq++) {
    float4 xv = xrow[dq];
    float xs[4] = {xv.x, xv.y, xv.z, xv.w};
#pragma unroll
    for (int t = 0; t < 4; t++) {
      const int d = dq * 4 + t;
      const float x = xs[t];
      const float xx = x * x;
      F8 mu = *reinterpret_cast<const F8*>(&smu[d * K_]);
      F8 cv = *reinterpret_cast<const F8*>(&scov[d * K_]);
#pragma unroll
      for (int k = 0; k < K_; k++) {
        a[k]  = fmaf(mu.f[k], x, a[k]);
        s2[k] = fmaf(cv.f[k], xx, s2[k]);
      }
    }
  }

  float4 w2[4], w1[4];
  float prod2 = 1.f, prod1 = 1.f;
#pragma unroll
  for (int k = 0; k < K_; k++) {
    const float b2 = 2.f * s2[k] + 1.f;
    const float b1 = 1.f + s2[k];
    reinterpret_cast<float*>(w2)[k]     = a[k];
    reinterpret_cast<float*>(w2)[8 + k] = L2E / b2;
    reinterpret_cast<float*>(w1)[k]     = a[k];
    reinterpret_cast<float*>(w1)[8 + k] = 0.5f * L2E / b1;
    prod2 *= rsqrtf(b2);
    prod1 *= rsqrtf(b1);
  }
  float4* a2q = reinterpret_cast<float4*>(ws + OFF_ARR2 + n * 16);
  float4* a1q = reinterpret_cast<float4*>(ws + OFF_ARR1 + n * 16);
#pragma unroll
  for (int e = 0; e < 4; e++) { a2q[e] = w2[e]; a1q[e] = w1[e]; }
  (ws + OFF_C2)[n] = prod2;
  (ws + OFF_CY)[n] = prod1 * Y[n];
}

// ---------------------------------------------------------------------------
// K2: 257 blocks.
//   b==0        : tail. Preload zl, A2's Kuu part, -Kuu^{-1} cols (registers)
//                 -> wait bar[17]=16 -> p2v from ws (regs) -> trace partial ->
//                 pipelined A2 sweep -> wait bar[16]=8 -> quad -> combine.
//   b>=1, t=b-1 : psi2 task (chunk t>>4, pairblk t&15) -> arrive bar[t&15].
//                 t<16 : wait bar[t]=16, reduce slice t -> arrive bar[17].
//                 16<=t<24 : Psi1^T Y chunk (t-16) -> arrive bar[16].
// ---------------------------------------------------------------------------
__global__ __launch_bounds__(256) void vdmgp_k2(
    const float* __restrict__ Z,
    const float* __restrict__ sfp, const float* __restrict__ nvp,
    float* __restrict__ ws, float* __restrict__ out) {
  __shared__ __align__(16) float pool[4864];

  int* bar = (int*)ws;
  const int tid = threadIdx.x;
  const int b = blockIdx.x;
  const float sf = sfp[0];

  if (b > 0) {
    const int t = b - 1;
    // -------- psi2 task (x4-unrolled inner loop) --------
    {
      float* sa = pool;           // 128*16
      float* sc = pool + 2048;    // 128
      const int chunk = t >> 4;
      const int nbase = chunk * 128;
      const float4* src = reinterpret_cast<const float4*>(ws + OFF_ARR2 + nbase * 16);
      float4* dst = reinterpret_cast<float4*>(sa);
      for (int idx = tid; idx < 128 * 4; idx += 256) dst[idx] = src[idx];
      if (tid < 128) sc[tid] = (ws + OFF_C2)[nbase + tid];
      __syncthreads();

      const int pair = (t & 15) * 256 + tid;
      const int i = pair >> 6, j = pair & 63;
      float zb[K_];
#pragma unroll
      for (int k = 0; k < K_; k++) zb[k] = 0.5f * (Z[i * K_ + k] + Z[j * K_ + k]);

      float acc = 0.f;
      for (int nl = 0; nl < 128; nl += 4) {
        F8 av0 = *reinterpret_cast<const F8*>(&sa[(nl + 0) * 16]);
        F8 ib0 = *reinterpret_cast<const F8*>(&sa[(nl + 0) * 16 + 8]);
        F8 av1 = *reinterpret_cast<const F8*>(&sa[(nl + 1) * 16]);
        F8 ib1 = *reinterpret_cast<const F8*>(&sa[(nl + 1) * 16 + 8]);
        F8 av2 = *reinterpret_cast<const F8*>(&sa[(nl + 2) * 16]);
        F8 ib2 = *reinterpret_cast<const F8*>(&sa[(nl + 2) * 16 + 8]);
        F8 av3 = *reinterpret_cast<const F8*>(&sa[(nl + 3) * 16]);
        F8 ib3 = *reinterpret_cast<const F8*>(&sa[(nl + 3) * 16 + 8]);
        float s0 = 0.f, s1 = 0.f, s2 = 0.f, s3 = 0.f;
#pragma unroll
        for (int k = 0; k < K_; k++) {
          const float d0 = av0.f[k] - zb[k]; s0 = fmaf(d0 * d0, ib0.f[k], s0);
          const float d1 = av1.f[k] - zb[k]; s1 = fmaf(d1 * d1, ib1.f[k], s1);
          const float d2 = av2.f[k] - zb[k]; s2 = fmaf(d2 * d2, ib2.f[k], s2);
          const float d3 = av3.f[k] - zb[k]; s3 = fmaf(d3 * d3, ib3.f[k], s3);
        }
        acc = fmaf(sc[nl + 0], exp2f(-s0), acc);
        acc = fmaf(sc[nl + 1], exp2f(-s1), acc);
        acc = fmaf(sc[nl + 2], exp2f(-s2), acc);
        acc = fmaf(sc[nl + 3], exp2f(-s3), acc);
      }
      (ws + OFF_P2P)[chunk * 4096 + (t & 15) * 256 + tid] = acc;
    }
    bar_arrive(&bar[t & 15]);

    if (t < 16) {
      // -------- reduce slice t: pairs [256t, 256t+256) --------
      bar_wait<4>(&bar[t], 16);
      const int p = t * 256 + tid;
      float acc = 0.f;
#pragma unroll
      for (int c = 0; c < 16; c++) acc += ws[OFF_P2P + c * 4096 + p];
      const int i = p >> 6, j = p & 63;
      float sq = 0.f;
#pragma unroll
      for (int k = 0; k < K_; k++) {
        const float dd = Z[i * K_ + k] - Z[j * K_ + k];
        sq = fmaf(dd, dd, sq);
      }
      ws[OFF_PSI2 + p] = sf * sf * exp2f(-0.25f * L2E * sq) * acc;
      bar_arrive(&bar[17]);
    } else if (t < 24) {
      // -------- Psi1^T Y chunk (t-16) --------
      float* sa1 = pool;          // 256*16
      float* scy = pool + 4096;   // 256
      float* red = pool + 4352;   // 256
      const int chunk = t - 16;
      const int nbase = chunk * 256;
      const float4* src = reinterpret_cast<const float4*>(ws + OFF_ARR1 + nbase * 16);
      float4* dst = reinterpret_cast<float4*>(sa1);
#pragma unroll
      for (int r = 0; r < 4; r++) dst[r * 256 + tid] = src[r * 256 + tid];
      scy[tid] = (ws + OFF_CY)[nbase + tid];
      __syncthreads();

      const int m = tid & 63;
      const int stripe = tid >> 6;
      float zm[K_];
#pragma unroll
      for (int k = 0; k < K_; k++) zm[k] = Z[m * K_ + k];

      float acc = 0.f;
      for (int u = 0; u < 64; u++) {
        const int nl = stripe * 64 + u;
        const F8 av = *reinterpret_cast<const F8*>(&sa1[nl * 16]);
        const F8 ib = *reinterpret_cast<const F8*>(&sa1[nl * 16 + 8]);
        float s = 0.f;
#pragma unroll
        for (int k = 0; k < K_; k++) {
          const float d = av.f[k] - zm[k];
          s = fmaf(d * d, ib.f[k], s);
        }
        acc = fmaf(scy[nl], exp2f(-s), acc);
      }
      red[tid] = acc;
      __syncthreads();
      if (tid < 64)
        (ws + OFF_P1Y)[chunk * 64 + tid] =
            red[tid] + red[64 + tid] + red[128 + tid] + red[192 + tid];
      bar_arrive(&bar[16]);
    }
    return;
  }

  // -------- b == 0: tail --------
  float (*zl)[9]         = reinterpret_cast<float(*)[9]>(pool);            // 576
  float (*rowbuf)[2][M_] = reinterpret_cast<float(*)[2][M_]>(pool + 576);  // 256
  float* pysL  = pool + 832;                                               // 64
  float* scalL = pool + 896;                                               // 8
  float* redQ  = pool + 912;                                               // 256
  float* redT  = pool + 1168;                                              // 256

  const int lane = tid & 63;
  const int wave = tid >> 6;
  const float s2v = nvp[0];

  for (int idx = tid; idx < M_ * K_; idx += 256) zl[idx >> 3][idx & 7] = Z[idx];
  __syncthreads();

  // preload (off critical path): A2's Kuu part and -Kuu^{-1} column slices
  float zj[K_];
#pragma unroll
  for (int k = 0; k < K_; k++) zj[k] = zl[lane][k];
  float base[16], kui16[16];
#pragma unroll
  for (int r = 0; r < 16; r++) {
    const int gi = 16 * wave + r;
    float sq = 0.f;
#pragma unroll
    for (int k = 0; k < K_; k++) { const float dd = zl[gi][k] - zj[k]; sq = fmaf(dd, dd, sq); }
    const float jit = (gi == lane) ? JIT : 0.f;
    base[r] = fmaf(s2v, exp2f(-0.5f * L2E * sq) + jit, jit);
    kui16[r] = ws[OFF_KUI + gi * 64 + lane];
  }

  bar_wait<2>(&bar[17], 16);    // reduced psi2 ready

  float reg[16];
  float sT = 0.f;
#pragma unroll
  for (int r = 0; r < 16; r++) {
    const int gi = 16 * wave + r;
    const float p2v = ws[OFF_PSI2 + gi * 64 + lane];
    reg[r] = base[r] + p2v;
    sT = fmaf(kui16[r], p2v, sT);
  }
  redT[tid] = sT;

  const float ld2 = sweep2x2_pipe(reg, rowbuf, wave, lane);

  bar_wait<2>(&bar[16], 8);     // p1y ready (normally long done)
  if (tid < M_) {
    float s = 0.f;
#pragma unroll
    for (int c = 0; c < 8; c++) s += ws[OFF_P1Y + c * M_ + tid];
    pysL[tid] = sf * s;
  }
  __syncthreads();

  float sQ = 0.f;
#pragma unroll
  for (int r = 0; r < 16; r++) sQ = fmaf(reg[r], pysL[16 * wave + r], sQ);
  redQ[tid] = sQ;
  __syncthreads();

  if (wave == 0) {
    float c = redQ[lane] + redQ[64 + lane] + redQ[128 + lane] + redQ[192 + lane];
    float q = c * pysL[lane];
#pragma unroll
    for (int off = 32; off > 0; off >>= 1) q += __shfl_down(q, off, 64);
    if (lane == 0) scalL[7] = -q;    // quad
  } else if (wave == 1) {
    float s = redT[lane] + redT[64 + lane] + redT[128 + lane] + redT[192 + lane];
#pragma unroll
    for (int off = 32; off > 0; off >>= 1) s += __shfl_down(s, off, 64);
    if (lane == 0) scalL[5] = -s;    // trace
  }
  __syncthreads();

  if (tid == 0) {
    const float YY  = ws[OFF_SC + 0];
    const float KL  = ws[OFF_SC + 1];
    const float ld1 = ws[OFF_SC + 2];
    const float tr = scalL[5], quad = scalL[7];
    const float inv = 1.0f / s2v;
    const float F1 = -(float)N_ * 1.8378770664093453f
                   - (float)(N_ - M_) * logf(s2v)
                   + (ld1 - LN2 * ld2)
                   - YY * inv
                   + quad * inv
                   - (float)N_ * sf * sf * inv
                   + tr * inv;
    out[0] = 0.5f * (F1 + KL);
  }
}

extern "C" void kernel_launch(void* const* d_in, const int* in_sizes, int n_in,
                              void* d_out, int out_size, void* d_ws, size_t ws_size,
                              hipStream_t stream) {
  const float* X    = (const float*)d_in[0];
  const float* Y    = (const float*)d_in[1];
  const float* qmu  = (const float*)d_in[2];
  const float* qcov = (const float*)d_in[3];
  const float* Z    = (const float*)d_in[4];
  const float* sfp  = (const float*)d_in[5];
  const float* nvp  = (const float*)d_in[6];
  float* ws  = (float*)d_ws;
  float* out = (float*)d_out;

  vdmgp_k1<<<10, 256, 0, stream>>>(X, Y, qmu, qcov, Z, ws);
  vdmgp_k2<<<257, 256, 0, stream>>>(Z, sfp, nvp, ws, out);
}